// Round 5
// baseline (375.682 us; speedup 1.0000x reference)
//
#include <hip/hip_runtime.h>

// Fixed shapes. I/O f32 (proven R7). Intermediates fp16, f32 accum.
#define T_SEQ 2048
#define DMODEL 2048
#define BSZ 2
#define MROWS (BSZ * T_SEQ)   // 4096 tokens
#define NQKV 4096             // 2048 q | 1024 k | 1024 v
#define NEG_BIG (-1e30f)

typedef __attribute__((ext_vector_type(8))) _Float16 half8;  // 16B, 4 VGPRs
typedef __attribute__((ext_vector_type(4))) _Float16 half4;  // 8B
typedef __attribute__((ext_vector_type(4))) float f32x4;     // MFMA acc

// async global->LDS, 16B per lane (dest = wave-uniform base + lane*16, linear)
typedef const __attribute__((address_space(1))) unsigned int* gas_ptr;
typedef __attribute__((address_space(3))) unsigned int* las_ptr;
#define GLD16(g, l) __builtin_amdgcn_global_load_lds((gas_ptr)(g), (las_ptr)(l), 16, 0, 0)

__device__ __forceinline__ unsigned short f2bf(float f) {
  unsigned u = __float_as_uint(f);
  unsigned r = (u + 0x7fffu + ((u >> 16) & 1u)) >> 16; // RNE
  return (unsigned short)r;
}
__device__ __forceinline__ float bf2f(unsigned short h) {
  return __uint_as_float(((unsigned)h) << 16);
}

// ---------------- RoPE tables (bf16 round-trip like reference) ----------------
__global__ void build_rope(float* __restrict__ cosT, float* __restrict__ sinT) {
  int t = blockIdx.x;    // 0..2047
  int i = threadIdx.x;   // 0..63
  float inv = (float)pow(10000.0, -((double)(2 * i)) / 128.0);
  float fr = (float)t * inv;
  cosT[t * 64 + i] = bf2f(f2bf(cosf(fr)));
  sinT[t * 64 + i] = bf2f(f2bf(sinf(fr)));
}

// ---------------- x (f32) -> fp16  AND  [Wq;Wk;Wv] (f32) -> fused (4096,2048) fp16 ----------------
__global__ __launch_bounds__(256) void cvt_xw(const float* __restrict__ x,
                                              const float* __restrict__ Wq,
                                              const float* __restrict__ Wk,
                                              const float* __restrict__ Wv,
                                              _Float16* __restrict__ xh,
                                              _Float16* __restrict__ wh) {
  int bid = blockIdx.x;
  size_t o = ((size_t)(bid & 4095) * 256 + threadIdx.x) * 8;
  const float* src;
  _Float16* dst;
  if (bid < 4096) {
    src = x + o;
    dst = xh + o;
  } else {
    int row = (int)(o >> 11), col = (int)(o & 2047);
    src = ((row < 2048) ? (Wq + (size_t)row * 2048)
          : (row < 3072) ? (Wk + (size_t)(row - 2048) * 2048)
                         : (Wv + (size_t)(row - 3072) * 2048)) + col;
    dst = wh + o;
  }
  float4 v0 = *(const float4*)(src);
  float4 v1 = *(const float4*)(src + 4);
  half8 r;
  r[0] = (_Float16)v0.x; r[1] = (_Float16)v0.y; r[2] = (_Float16)v0.z; r[3] = (_Float16)v0.w;
  r[4] = (_Float16)v1.x; r[5] = (_Float16)v1.y; r[6] = (_Float16)v1.z; r[7] = (_Float16)v1.w;
  *(half8*)(dst) = r;
}

// ---------------- NT GEMM v2: qkv[M,4096] = xh[M,K] * wh[4096,K]^T (proven R3) ----------------
__global__ __launch_bounds__(256) void gemm_nt(const _Float16* __restrict__ A,
                                               const _Float16* __restrict__ Bw,
                                               _Float16* __restrict__ C) {
  const int K = DMODEL, N = NQKV;
  __shared__ __align__(16) char As[2][128 * 128];  // 16KB per buf (128 rows x 128B)
  __shared__ __align__(16) char Bs[2][128 * 128];  // total LDS 64KB -> 2 blocks/CU
  int tid = threadIdx.x;
  int lane = tid & 63, w = tid >> 6;
  int wm = w >> 1, wn = w & 1;
  int l15 = lane & 15, quad = lane >> 4;
  int bm = blockIdx.y, bn = blockIdx.x;

  const char* Aab = (const char*)(A + (size_t)(bm * 128) * K);
  const char* Bab = (const char*)(Bw + (size_t)(bn * 128) * K);
  int srow = lane >> 3;                      // 0..7: row within 8-row chunk
  int scol = ((lane & 7) ^ srow) << 4;       // pre-swizzled byte col within 128B row

  // wave w stages rows [w*32, w*32+32): 4 chunks x 1KB per matrix
  auto stage = [&](int t) {
    int buf = t & 1;
    size_t kb = (size_t)t << 7;              // t*64 halves = t*128 bytes along K
#pragma unroll
    for (int g = 0; g < 4; g++) {
      int row = w * 32 + g * 8 + srow;
      GLD16(Aab + (size_t)row * (K * 2) + kb + scol, &As[buf][w * 4096 + g * 1024]);
    }
#pragma unroll
    for (int g = 0; g < 4; g++) {
      int row = w * 32 + g * 8 + srow;
      GLD16(Bab + (size_t)row * (K * 2) + kb + scol, &Bs[buf][w * 4096 + g * 1024]);
    }
  };

  f32x4 acc[4][4];
#pragma unroll
  for (int i = 0; i < 4; i++)
#pragma unroll
    for (int j = 0; j < 4; j++) acc[i][j] = (f32x4){0.f, 0.f, 0.f, 0.f};

  stage(0);
  for (int t = 0; t < 32; t++) {
    if (t < 31) {
      stage(t + 1);
      asm volatile("s_waitcnt vmcnt(8)" ::: "memory");  // t's 8 done; t+1's 8 in flight
    } else {
      asm volatile("s_waitcnt vmcnt(0)" ::: "memory");
    }
    __builtin_amdgcn_s_barrier();
    __builtin_amdgcn_sched_barrier(0);

    const char* ab = As[t & 1];
    const char* bb = Bs[t & 1];
#pragma unroll
    for (int kc = 0; kc < 2; kc++) {
      half8 af[4], bfr[4];
#pragma unroll
      for (int i = 0; i < 4; i++) {
        int row = wm * 64 + i * 16 + l15;
        af[i] = *(const half8*)(ab + row * 128 + ((kc * 64 + quad * 16) ^ ((row & 7) << 4)));
      }
#pragma unroll
      for (int j = 0; j < 4; j++) {
        int row = wn * 64 + j * 16 + l15;
        bfr[j] = *(const half8*)(bb + row * 128 + ((kc * 64 + quad * 16) ^ ((row & 7) << 4)));
      }
#pragma unroll
      for (int i = 0; i < 4; i++)
#pragma unroll
        for (int j = 0; j < 4; j++)
          acc[i][j] = __builtin_amdgcn_mfma_f32_16x16x32_f16(af[i], bfr[j], acc[i][j], 0, 0, 0);
    }

    asm volatile("s_waitcnt lgkmcnt(0)" ::: "memory");  // this wave's ds_reads done
    __builtin_amdgcn_s_barrier();                       // buf t&1 free for stage(t+2)
    __builtin_amdgcn_sched_barrier(0);
  }

#pragma unroll
  for (int i = 0; i < 4; i++)
#pragma unroll
    for (int j = 0; j < 4; j++)
#pragma unroll
      for (int r = 0; r < 4; r++) {
        int row = bm * 128 + wm * 64 + i * 16 + quad * 4 + r;
        int col = bn * 128 + wn * 64 + j * 16 + l15;
        C[(size_t)row * N + col] = (_Float16)acc[i][j][r];
      }
}

// ---------------- RMSNorm + RoPE v2: wave-parallel, vectorized, zero LDS (proven R4) ----------------
__global__ __launch_bounds__(256) void postproc(_Float16* __restrict__ qkv,
                                                const float* __restrict__ cosT,
                                                const float* __restrict__ sinT,
                                                _Float16* __restrict__ kp) {
  int tid = threadIdx.x, lane = tid & 63, w = tid >> 6;
  int h = blockIdx.y;                                   // 0..23
  int tkn = blockIdx.x * 16 + w * 4 + (lane >> 4);      // 0..4095
  int b = tkn >> 11, t = tkn & 2047;
  int l15 = lane & 15;
  int col0 = (h < 16) ? (h * 128) : (2048 + (h - 16) * 128);
  size_t base = (size_t)tkn * NQKV + col0 + l15 * 8;

  half8 v = *(const half8*)(qkv + base);
  float xf[8];
  float ss = 0.f;
#pragma unroll
  for (int j = 0; j < 8; j++) { xf[j] = (float)v[j]; ss += xf[j] * xf[j]; }
  ss += __shfl_xor(ss, 1, 64);
  ss += __shfl_xor(ss, 2, 64);
  ss += __shfl_xor(ss, 4, 64);
  ss += __shfl_xor(ss, 8, 64);
  float rn = rsqrtf(ss * (1.0f / 128.0f) + 1.1920929e-7f);

  const float* cb = cosT + t * 64 + (lane & 7) * 8;
  const float* sb = sinT + t * 64 + (lane & 7) * 8;
  float4 c0 = *(const float4*)cb, c1 = *(const float4*)(cb + 4);
  float4 s0 = *(const float4*)sb, s1 = *(const float4*)(sb + 4);
  float cc[8] = {c0.x, c0.y, c0.z, c0.w, c1.x, c1.y, c1.z, c1.w};
  float sn[8] = {s0.x, s0.y, s0.z, s0.w, s1.x, s1.y, s1.z, s1.w};
  float sgn = (lane & 8) ? -1.f : 1.f;

  half8 o;
#pragma unroll
  for (int j = 0; j < 8; j++) {
    float xn = xf[j] * rn;
    float xp = __shfl_xor(xn, 8, 64);   // partner dim d +/- 64
    o[j] = (_Float16)(xn * cc[j] + sgn * xp * sn[j]);
  }
  if (h < 16)
    *(half8*)(qkv + base) = o;
  else
    *(half8*)(kp + (((size_t)(b * 8 + (h - 16))) * T_SEQ + t) * 128 + l15 * 8) = o;
}

// ---------------- V: transpose qkv v-cols -> (B, 4, 256, T) fp16 ----------------
__global__ void transpose_v(const _Float16* __restrict__ qkv,
                            _Float16* __restrict__ vt) {
  __shared__ _Float16 tile[32][33];
  int t0 = blockIdx.x * 32, d0 = blockIdx.y * 32;
  int bz = blockIdx.z;
  int b = bz >> 2, vh = bz & 3;
  int tx = threadIdx.x, ty = threadIdx.y;
#pragma unroll
  for (int i = 0; i < 4; i++) {
    int t = t0 + ty + i * 8;
    tile[ty + i * 8][tx] = qkv[((size_t)(b * T_SEQ + t)) * NQKV + 3072 + vh * 256 + d0 + tx];
  }
  __syncthreads();
#pragma unroll
  for (int i = 0; i < 4; i++) {
    int d = d0 + ty + i * 8;
    vt[(((size_t)(b * 4 + vh)) * 256 + d) * T_SEQ + t0 + tx] = tile[tx][ty + i * 8];
  }
}

// ---------------- causal flash attention v6 ----------------
// = v5 softmax (exp2-domain + T13 defer-max; counter-verified VALU savings) on the
// R3 grid mapping dim3(16,8,4). The R4 XCD swizzle is REVERTED: it achieved L2
// locality (FETCH 130->29.5MB) but put all 16 blocks of a combo in lockstep on one
// XCD's L2 -> same-line bank serialization, +2000 cy/tile stall. Spreading across
// XCDs (L3-served, 1.7 TB/s) is faster; this kernel is latency/VALU-bound, not BW-bound.
__global__ __launch_bounds__(256) void attn(const _Float16* __restrict__ qkv,
                                            const _Float16* __restrict__ kp,
                                            const _Float16* __restrict__ vt,
                                            const float* __restrict__ scaler,
                                            float* __restrict__ y1out,
                                            _Float16* __restrict__ y2out) {
  __shared__ __align__(16) char Ks[2][64 * 256];   // 32 KB: K tile, dbuf (256B rows, swizzled)
  __shared__ __align__(16) char Vs[2][128 * 128];  // 32 KB: V^T halves (128B rows, swizzled)
  __shared__ _Float16 Pt[4 * 16 * 72];             // 9 KB: per-wave P (A-operand layout)
  // total LDS 74752 B -> 2 blocks/CU

  int tid = threadIdx.x, lane = tid & 63, w = tid >> 6;
  int l15 = lane & 15, quad = lane >> 4;
  int bx = blockIdx.x, hh = blockIdx.y, z = blockIdx.z;
  int b = z >> 1, br = z & 1;
  int qh = br * 8 + hh;
  int kh = br * 4 + (hh >> 1);
  int vh = hh >> 1;

  const char* kbase_b = (const char*)(kp + ((size_t)(b * 8 + kh)) * T_SEQ * 128);
  const char* vbase_b = (const char*)(vt + ((size_t)(b * 4 + vh)) * 256 * T_SEQ);
  _Float16* pw = &Pt[w * 16 * 72];
  float sc = scaler[qh] * 0.08838834764831844f; // 1/sqrt(128)

  // staging lane constants
  int krow_l = lane >> 4;          // row within 4-row K chunk
  int kpc    = (lane & 15) << 4;   // byte col within 256B K row
  int vrow_l = lane >> 3;          // row within 8-row V chunk
  int vpc    = (lane & 7) << 4;    // byte col within 128B V row

  // wave w stages K rows 16w..16w+15 (4 chunks x 1KB) and V dims 32w..32w+31 per half
  auto stageK = [&](int kt1) {
    int ksr = kt1 * 64;
    char* dstb = Ks[kt1 & 1];
#pragma unroll
    for (int c2 = 0; c2 < 4; c2++) {
      int cc = w * 4 + c2;
      int row = cc * 4 + krow_l;
      const char* src = kbase_b + (((size_t)(ksr + row)) << 8) + (kpc ^ ((row & 7) << 4));
      GLD16(src, dstb + (cc << 10));
    }
  };
  auto stageV = [&](int kt1) {
    int ksb = kt1 * 128; // key-start byte offset within a V row
#pragma unroll
    for (int h = 0; h < 2; h++)
#pragma unroll
      for (int c2 = 0; c2 < 4; c2++) {
        int cc = w * 4 + c2;
        int d = h * 128 + cc * 8 + vrow_l;
        const char* src = vbase_b + (size_t)d * (T_SEQ * 2) + ksb + (vpc ^ (vrow_l << 4));
        GLD16(src, Vs[h] + (cc << 10));
      }
  };

  for (int half = 0; half < 2; half++) {
    int qt = half ? (31 - bx) : bx;
    int t0 = qt * 64;
    int tg = t0 + w * 16 + l15;  // this lane's query row (swapped layout)

    // Q fragments (B-operand: n = lane&15, k = quad*8+j); q in-place, row stride NQKV
    const _Float16* qbase = qkv + ((size_t)(b * T_SEQ + tg)) * NQKV + qh * 128;
    half8 qf[4];
#pragma unroll
    for (int kc = 0; kc < 4; kc++)
      qf[kc] = *(const half8*)(qbase + kc * 32 + quad * 8);

    // prologue: async-stage tile 0 (prev half's last barrier guarantees buffers free)
    stageK(0);
    stageV(0);
    __builtin_amdgcn_sched_barrier(0);

    float mrow = NEG_BIG, lrow = 0.f;          // per-lane: query = lane&15 (log2 domain)
    float rowscale = sc * logf((float)(tg + 1)) * 1.44269504f;  // fold log2(e)
    f32x4 acc[16];
#pragma unroll
    for (int nb = 0; nb < 16; nb++) acc[nb] = (f32x4){0.f, 0.f, 0.f, 0.f};

    for (int kt = 0; kt <= qt; kt++) {
      int ks = kt * 64;
      bool notlast = (kt < qt);

      // (A) K(kt) ready; V(kt) stays in flight
      asm volatile("s_waitcnt vmcnt(8)" ::: "memory");
      __builtin_amdgcn_s_barrier();
      __builtin_amdgcn_sched_barrier(0);
      if (notlast) stageK(kt + 1);

      // (B) S^T = K Q^T from LDS (swizzled ds_read_b128); row=key, col=query
      const char* kbuf = Ks[kt & 1];
      f32x4 sv[4];
#pragma unroll
      for (int j = 0; j < 4; j++) {
        int row = j * 16 + l15;
        int sw = (row & 7) << 4;
        const char* kr = kbuf + (row << 8);
        half8 kf0 = *(const half8*)(kr + (((quad << 4) + 0) ^ sw));
        half8 kf1 = *(const half8*)(kr + (((quad << 4) + 64) ^ sw));
        half8 kf2 = *(const half8*)(kr + (((quad << 4) + 128) ^ sw));
        half8 kf3 = *(const half8*)(kr + (((quad << 4) + 192) ^ sw));
        f32x4 a = (f32x4){0.f, 0.f, 0.f, 0.f};
        a = __builtin_amdgcn_mfma_f32_16x16x32_f16(kf0, qf[0], a, 0, 0, 0);
        a = __builtin_amdgcn_mfma_f32_16x16x32_f16(kf1, qf[1], a, 0, 0, 0);
        a = __builtin_amdgcn_mfma_f32_16x16x32_f16(kf2, qf[2], a, 0, 0, 0);
        a = __builtin_amdgcn_mfma_f32_16x16x32_f16(kf3, qf[3], a, 0, 0, 0);
        sv[j] = a;
      }

      // (C) softmax — lane-local over 16 scores of query l15, log2 domain
      bool diag = (kt == qt);
      float s_r[16];
      float mx = NEG_BIG;
#pragma unroll
      for (int j = 0; j < 4; j++)
#pragma unroll
        for (int r = 0; r < 4; r++) {
          float s = sv[j][r] * rowscale;
          if (diag) {
            int kg = ks + j * 16 + quad * 4 + r;
            if (kg > tg) s = NEG_BIG;
          }
          s_r[j * 4 + r] = s;
          mx = fmaxf(mx, s);
        }
      mx = fmaxf(mx, __shfl_xor(mx, 16, 64));
      mx = fmaxf(mx, __shfl_xor(mx, 32, 64));
      // T13 defer-max: only rescale when tile max grew past threshold (log2 units)
      if (__any(mx > mrow + 8.0f)) {
        float mnew = fmaxf(mrow, mx);
        float alpha = exp2f(mrow - mnew);
        mrow = mnew;
        lrow *= alpha;
        float at[4];
#pragma unroll
        for (int r = 0; r < 4; r++) at[r] = __shfl(alpha, quad * 20 + r, 64);
#pragma unroll
        for (int nb = 0; nb < 16; nb++)
#pragma unroll
          for (int r = 0; r < 4; r++) acc[nb][r] *= at[r];
      }
      float p[16];
      float rs = 0.f;
#pragma unroll
      for (int i = 0; i < 16; i++) {
        p[i] = exp2f(s_r[i] - mrow);
        rs += p[i];
      }
      rs += __shfl_xor(rs, 16, 64);
      rs += __shfl_xor(rs, 32, 64);
      lrow += rs;

      // (D) P -> LDS (packed b64) -> A-operand fragments (wave-private; no barrier)
#pragma unroll
      for (int j = 0; j < 4; j++) {
        half4 pk;
        pk[0] = (_Float16)p[j * 4 + 0];
        pk[1] = (_Float16)p[j * 4 + 1];
        pk[2] = (_Float16)p[j * 4 + 2];
        pk[3] = (_Float16)p[j * 4 + 3];
        *(half4*)&pw[l15 * 72 + j * 16 + quad * 4] = pk;
      }
      half8 pf0 = *(const half8*)&pw[l15 * 72 + quad * 8];
      half8 pf1 = *(const half8*)&pw[l15 * 72 + 32 + quad * 8];

      // (E) publish Vs: drain V(kt), keep K(kt+1) in flight
      if (notlast)
        asm volatile("s_waitcnt vmcnt(4)" ::: "memory");
      else
        asm volatile("s_waitcnt vmcnt(0)" ::: "memory");
      __builtin_amdgcn_s_barrier();
      __builtin_amdgcn_sched_barrier(0);

      // (F) O += P V from LDS (swizzled ds_read_b128)
#pragma unroll
      for (int h = 0; h < 2; h++) {
#pragma unroll
        for (int nbl = 0; nbl < 8; nbl++) {
          int row = nbl * 16 + l15;
          int sw = (row & 7) << 4;
          const char* vr = Vs[h] + (row << 7);
          half8 vf0 = *(const half8*)(vr + (((quad << 4) + 0) ^ sw));
          half8 vf1 = *(const half8*)(vr + (((quad << 4) + 64) ^ sw));
          int nb = h * 8 + nbl;
          acc[nb] = __builtin_amdgcn_mfma_f32_16x16x32_f16(pf0, vf0, acc[nb], 0, 0, 0);
          acc[nb] = __builtin_amdgcn_mfma_f32_16x16x32_f16(pf1, vf1, acc[nb], 0, 0, 0);
        }
      }

      // (G) Vs consumed by all waves -> prefetch V(kt+1)
      asm volatile("s_waitcnt lgkmcnt(0)" ::: "memory");
      __builtin_amdgcn_s_barrier();
      __builtin_amdgcn_sched_barrier(0);
      if (notlast) stageV(kt + 1);
    }

    // epilogue: divide by l (redistributed to acc domain); y1 -> f32, y2 -> fp16
    float linv = 1.0f / lrow;
    float lt[4];
#pragma unroll
    for (int r = 0; r < 4; r++) lt[r] = __shfl(linv, quad * 20 + r, 64);
#pragma unroll
    for (int r = 0; r < 4; r++) {
      int tr = t0 + w * 16 + quad * 4 + r;
      size_t base = ((size_t)(b * T_SEQ + tr)) * 2048 + hh * 256;
      if (br) {
#pragma unroll
        for (int nb = 0; nb < 16; nb++)
          y2out[base + nb * 16 + l15] = (_Float16)(acc[nb][r] * lt[r]);
      } else {
#pragma unroll
        for (int nb = 0; nb < 16; nb++)
          y1out[base + nb * 16 + l15] = acc[nb][r] * lt[r];
      }
    }
  }
}

// ---------------- out = y1 - lam * y2 (f32, in place on d_out) ----------------
__global__ __launch_bounds__(256) void combine(float* __restrict__ out,
                                               const _Float16* __restrict__ y2,
                                               const float* __restrict__ lq1,
                                               const float* __restrict__ lk1,
                                               const float* __restrict__ lq2,
                                               const float* __restrict__ lk2) {
  int lane = threadIdx.x & 63;
  float a = lq1[lane] * lk1[lane];
  float bb = lq2[lane] * lk2[lane];
#pragma unroll
  for (int m = 1; m < 64; m <<= 1) {
    a += __shfl_xor(a, m, 64);
    bb += __shfl_xor(bb, m, 64);
  }
  float lam = expf(a) - expf(bb) + 0.2f;

  size_t o = ((size_t)blockIdx.x * 256 + threadIdx.x) * 8;
  half8 yv = *(const half8*)(y2 + o);
  float4 a0 = *(float4*)(out + o);
  float4 a1 = *(float4*)(out + o + 4);
  a0.x -= lam * (float)yv[0];
  a0.y -= lam * (float)yv[1];
  a0.z -= lam * (float)yv[2];
  a0.w -= lam * (float)yv[3];
  a1.x -= lam * (float)yv[4];
  a1.y -= lam * (float)yv[5];
  a1.z -= lam * (float)yv[6];
  a1.w -= lam * (float)yv[7];
  *(float4*)(out + o) = a0;
  *(float4*)(out + o + 4) = a1;
}

extern "C" void kernel_launch(void* const* d_in, const int* in_sizes, int n_in,
                              void* d_out, int out_size, void* d_ws, size_t ws_size,
                              hipStream_t stream) {
  const float* x   = (const float*)d_in[0];
  const float* Wq  = (const float*)d_in[1];
  const float* Wk  = (const float*)d_in[2];
  const float* Wv  = (const float*)d_in[3];
  const float* lq1 = (const float*)d_in[4];
  const float* lk1 = (const float*)d_in[5];
  const float* lq2 = (const float*)d_in[6];
  const float* lk2 = (const float*)d_in[7];
  const float* scaler = (const float*)d_in[8];
  float* out = (float*)d_out;

  char* W = (char*)d_ws;
  // Workspace high-water 64 MiB (proven safe):
  // Phase 1 (until gemm done): xh [0,16.78M), wh [16.78,33.55M), qkvh [33.55,67.11M)
  // Phase 2 (after gemm, xh/wh dead): kp [0,8.39M), vtb [8.39,16.78M), y2h [16.78,33.55M)
  // RoPE tables live in d_out[0, 1.05MB) (free until attn writes y1 there).
  _Float16* xh   = (_Float16*)(W + 0);
  _Float16* wh   = (_Float16*)(W + 16777216);
  _Float16* qkvh = (_Float16*)(W + 33554432);
  _Float16* kph  = (_Float16*)(W + 0);
  _Float16* vtb  = (_Float16*)(W + 8388608);
  _Float16* y2h  = (_Float16*)(W + 16777216);
  float* cosT    = out;            // 2048*64 f32 = 0.52 MB
  float* sinT    = out + 131072;   // 0.52 MB (ends at 1.05 MB)

  build_rope<<<T_SEQ, 64, 0, stream>>>(cosT, sinT);
  cvt_xw<<<8192, 256, 0, stream>>>(x, Wq, Wk, Wv, xh, wh);
  gemm_nt<<<dim3(NQKV / 128, MROWS / 128), 256, 0, stream>>>(xh, wh, qkvh);
  postproc<<<dim3(256, 24), 256, 0, stream>>>(qkvh, cosT, sinT, kph);
  transpose_v<<<dim3(T_SEQ / 32, 256 / 32, BSZ * 4), dim3(32, 8), 0, stream>>>(qkvh, vtb);
  attn<<<dim3(16, 8, BSZ * 2), 256, 0, stream>>>(qkvh, kph, vtb, scaler, out, y2h);
  combine<<<4096, 256, 0, stream>>>(out, y2h, lq1, lk1, lq2, lk2);
}

// Round 6
// 316.392 us; speedup vs baseline: 1.1874x; 1.1874x over previous
//
#include <hip/hip_runtime.h>

// Fixed shapes. I/O f32 (proven R7). Intermediates fp16, f32 accum.
#define T_SEQ 2048
#define DMODEL 2048
#define BSZ 2
#define MROWS (BSZ * T_SEQ)   // 4096 tokens
#define NQKV 4096             // 2048 q | 1024 k | 1024 v
#define NEG_BIG (-1e30f)

typedef __attribute__((ext_vector_type(8))) _Float16 half8;  // 16B, 4 VGPRs
typedef __attribute__((ext_vector_type(4))) _Float16 half4;  // 8B
typedef __attribute__((ext_vector_type(4))) float f32x4;     // MFMA acc

// async global->LDS, 16B per lane (dest = wave-uniform base + lane*16, linear)
typedef const __attribute__((address_space(1))) unsigned int* gas_ptr;
typedef __attribute__((address_space(3))) unsigned int* las_ptr;
#define GLD16(g, l) __builtin_amdgcn_global_load_lds((gas_ptr)(g), (las_ptr)(l), 16, 0, 0)

__device__ __forceinline__ unsigned short f2bf(float f) {
  unsigned u = __float_as_uint(f);
  unsigned r = (u + 0x7fffu + ((u >> 16) & 1u)) >> 16; // RNE
  return (unsigned short)r;
}
__device__ __forceinline__ float bf2f(unsigned short h) {
  return __uint_as_float(((unsigned)h) << 16);
}

// ---------------- RoPE tables (bf16 round-trip like reference) ----------------
__global__ void build_rope(float* __restrict__ cosT, float* __restrict__ sinT) {
  int t = blockIdx.x;    // 0..2047
  int i = threadIdx.x;   // 0..63
  float inv = (float)pow(10000.0, -((double)(2 * i)) / 128.0);
  float fr = (float)t * inv;
  cosT[t * 64 + i] = bf2f(f2bf(cosf(fr)));
  sinT[t * 64 + i] = bf2f(f2bf(sinf(fr)));
}

// ---------------- x (f32) -> fp16  AND  [Wq;Wk;Wv] (f32) -> fused (4096,2048) fp16 ----------------
__global__ __launch_bounds__(256) void cvt_xw(const float* __restrict__ x,
                                              const float* __restrict__ Wq,
                                              const float* __restrict__ Wk,
                                              const float* __restrict__ Wv,
                                              _Float16* __restrict__ xh,
                                              _Float16* __restrict__ wh) {
  int bid = blockIdx.x;
  size_t o = ((size_t)(bid & 4095) * 256 + threadIdx.x) * 8;
  const float* src;
  _Float16* dst;
  if (bid < 4096) {
    src = x + o;
    dst = xh + o;
  } else {
    int row = (int)(o >> 11), col = (int)(o & 2047);
    src = ((row < 2048) ? (Wq + (size_t)row * 2048)
          : (row < 3072) ? (Wk + (size_t)(row - 2048) * 2048)
                         : (Wv + (size_t)(row - 3072) * 2048)) + col;
    dst = wh + o;
  }
  float4 v0 = *(const float4*)(src);
  float4 v1 = *(const float4*)(src + 4);
  half8 r;
  r[0] = (_Float16)v0.x; r[1] = (_Float16)v0.y; r[2] = (_Float16)v0.z; r[3] = (_Float16)v0.w;
  r[4] = (_Float16)v1.x; r[5] = (_Float16)v1.y; r[6] = (_Float16)v1.z; r[7] = (_Float16)v1.w;
  *(half8*)(dst) = r;
}

// ---------------- NT GEMM v2: qkv[M,4096] = xh[M,K] * wh[4096,K]^T (proven R3) ----------------
__global__ __launch_bounds__(256) void gemm_nt(const _Float16* __restrict__ A,
                                               const _Float16* __restrict__ Bw,
                                               _Float16* __restrict__ C) {
  const int K = DMODEL, N = NQKV;
  __shared__ __align__(16) char As[2][128 * 128];  // 16KB per buf (128 rows x 128B)
  __shared__ __align__(16) char Bs[2][128 * 128];  // total LDS 64KB -> 2 blocks/CU
  int tid = threadIdx.x;
  int lane = tid & 63, w = tid >> 6;
  int wm = w >> 1, wn = w & 1;
  int l15 = lane & 15, quad = lane >> 4;
  int bm = blockIdx.y, bn = blockIdx.x;

  const char* Aab = (const char*)(A + (size_t)(bm * 128) * K);
  const char* Bab = (const char*)(Bw + (size_t)(bn * 128) * K);
  int srow = lane >> 3;                      // 0..7: row within 8-row chunk
  int scol = ((lane & 7) ^ srow) << 4;       // pre-swizzled byte col within 128B row

  // wave w stages rows [w*32, w*32+32): 4 chunks x 1KB per matrix
  auto stage = [&](int t) {
    int buf = t & 1;
    size_t kb = (size_t)t << 7;              // t*64 halves = t*128 bytes along K
#pragma unroll
    for (int g = 0; g < 4; g++) {
      int row = w * 32 + g * 8 + srow;
      GLD16(Aab + (size_t)row * (K * 2) + kb + scol, &As[buf][w * 4096 + g * 1024]);
    }
#pragma unroll
    for (int g = 0; g < 4; g++) {
      int row = w * 32 + g * 8 + srow;
      GLD16(Bab + (size_t)row * (K * 2) + kb + scol, &Bs[buf][w * 4096 + g * 1024]);
    }
  };

  f32x4 acc[4][4];
#pragma unroll
  for (int i = 0; i < 4; i++)
#pragma unroll
    for (int j = 0; j < 4; j++) acc[i][j] = (f32x4){0.f, 0.f, 0.f, 0.f};

  stage(0);
  for (int t = 0; t < 32; t++) {
    if (t < 31) {
      stage(t + 1);
      asm volatile("s_waitcnt vmcnt(8)" ::: "memory");  // t's 8 done; t+1's 8 in flight
    } else {
      asm volatile("s_waitcnt vmcnt(0)" ::: "memory");
    }
    __builtin_amdgcn_s_barrier();
    __builtin_amdgcn_sched_barrier(0);

    const char* ab = As[t & 1];
    const char* bb = Bs[t & 1];
#pragma unroll
    for (int kc = 0; kc < 2; kc++) {
      half8 af[4], bfr[4];
#pragma unroll
      for (int i = 0; i < 4; i++) {
        int row = wm * 64 + i * 16 + l15;
        af[i] = *(const half8*)(ab + row * 128 + ((kc * 64 + quad * 16) ^ ((row & 7) << 4)));
      }
#pragma unroll
      for (int j = 0; j < 4; j++) {
        int row = wn * 64 + j * 16 + l15;
        bfr[j] = *(const half8*)(bb + row * 128 + ((kc * 64 + quad * 16) ^ ((row & 7) << 4)));
      }
#pragma unroll
      for (int i = 0; i < 4; i++)
#pragma unroll
        for (int j = 0; j < 4; j++)
          acc[i][j] = __builtin_amdgcn_mfma_f32_16x16x32_f16(af[i], bfr[j], acc[i][j], 0, 0, 0);
    }

    asm volatile("s_waitcnt lgkmcnt(0)" ::: "memory");  // this wave's ds_reads done
    __builtin_amdgcn_s_barrier();                       // buf t&1 free for stage(t+2)
    __builtin_amdgcn_sched_barrier(0);
  }

#pragma unroll
  for (int i = 0; i < 4; i++)
#pragma unroll
    for (int j = 0; j < 4; j++)
#pragma unroll
      for (int r = 0; r < 4; r++) {
        int row = bm * 128 + wm * 64 + i * 16 + quad * 4 + r;
        int col = bn * 128 + wn * 64 + j * 16 + l15;
        C[(size_t)row * N + col] = (_Float16)acc[i][j][r];
      }
}

// ---------------- RMSNorm + RoPE v2: wave-parallel, vectorized, zero LDS (proven R4) ----------------
__global__ __launch_bounds__(256) void postproc(_Float16* __restrict__ qkv,
                                                const float* __restrict__ cosT,
                                                const float* __restrict__ sinT,
                                                _Float16* __restrict__ kp) {
  int tid = threadIdx.x, lane = tid & 63, w = tid >> 6;
  int h = blockIdx.y;                                   // 0..23
  int tkn = blockIdx.x * 16 + w * 4 + (lane >> 4);      // 0..4095
  int b = tkn >> 11, t = tkn & 2047;
  int l15 = lane & 15;
  int col0 = (h < 16) ? (h * 128) : (2048 + (h - 16) * 128);
  size_t base = (size_t)tkn * NQKV + col0 + l15 * 8;

  half8 v = *(const half8*)(qkv + base);
  float xf[8];
  float ss = 0.f;
#pragma unroll
  for (int j = 0; j < 8; j++) { xf[j] = (float)v[j]; ss += xf[j] * xf[j]; }
  ss += __shfl_xor(ss, 1, 64);
  ss += __shfl_xor(ss, 2, 64);
  ss += __shfl_xor(ss, 4, 64);
  ss += __shfl_xor(ss, 8, 64);
  float rn = rsqrtf(ss * (1.0f / 128.0f) + 1.1920929e-7f);

  const float* cb = cosT + t * 64 + (lane & 7) * 8;
  const float* sb = sinT + t * 64 + (lane & 7) * 8;
  float4 c0 = *(const float4*)cb, c1 = *(const float4*)(cb + 4);
  float4 s0 = *(const float4*)sb, s1 = *(const float4*)(sb + 4);
  float cc[8] = {c0.x, c0.y, c0.z, c0.w, c1.x, c1.y, c1.z, c1.w};
  float sn[8] = {s0.x, s0.y, s0.z, s0.w, s1.x, s1.y, s1.z, s1.w};
  float sgn = (lane & 8) ? -1.f : 1.f;

  half8 o;
#pragma unroll
  for (int j = 0; j < 8; j++) {
    float xn = xf[j] * rn;
    float xp = __shfl_xor(xn, 8, 64);   // partner dim d +/- 64
    o[j] = (_Float16)(xn * cc[j] + sgn * xp * sn[j]);
  }
  if (h < 16)
    *(half8*)(qkv + base) = o;
  else
    *(half8*)(kp + (((size_t)(b * 8 + (h - 16))) * T_SEQ + t) * 128 + l15 * 8) = o;
}

// ---------------- V: transpose qkv v-cols -> (B, 4, 256, T) fp16 ----------------
__global__ void transpose_v(const _Float16* __restrict__ qkv,
                            _Float16* __restrict__ vt) {
  __shared__ _Float16 tile[32][33];
  int t0 = blockIdx.x * 32, d0 = blockIdx.y * 32;
  int bz = blockIdx.z;
  int b = bz >> 2, vh = bz & 3;
  int tx = threadIdx.x, ty = threadIdx.y;
#pragma unroll
  for (int i = 0; i < 4; i++) {
    int t = t0 + ty + i * 8;
    tile[ty + i * 8][tx] = qkv[((size_t)(b * T_SEQ + t)) * NQKV + 3072 + vh * 256 + d0 + tx];
  }
  __syncthreads();
#pragma unroll
  for (int i = 0; i < 4; i++) {
    int d = d0 + ty + i * 8;
    vt[(((size_t)(b * 4 + vh)) * 256 + d) * T_SEQ + t0 + tx] = tile[tx][ty + i * 8];
  }
}

// ---------------- causal flash attention v7 = R3-exact softmax on R3 grid ----------------
// Post-mortem R4/R5: the exp2+defer-max branch (R4) was the regression, NOT the XCD
// swizzle. Busy time was identical (MFMA 22.5->21.8us, VALU 49->46us) but stall grew
// ~60us: a data-dependent branch inside the counted-vmcnt barrier pipeline breaks the
// compiler's cross-phase scheduling and skews wave arrival at barriers. Rule: NO
// conditional control flow inside this loop. Softmax restored to R3's straight-line
// form (measured 110us).
__global__ __launch_bounds__(256) void attn(const _Float16* __restrict__ qkv,
                                            const _Float16* __restrict__ kp,
                                            const _Float16* __restrict__ vt,
                                            const float* __restrict__ scaler,
                                            float* __restrict__ y1out,
                                            _Float16* __restrict__ y2out) {
  __shared__ __align__(16) char Ks[2][64 * 256];   // 32 KB: K tile, dbuf (256B rows, swizzled)
  __shared__ __align__(16) char Vs[2][128 * 128];  // 32 KB: V^T halves (128B rows, swizzled)
  __shared__ _Float16 Pt[4 * 16 * 72];             // 9 KB: per-wave P (A-operand layout)
  // total LDS 74752 B -> 2 blocks/CU

  int tid = threadIdx.x, lane = tid & 63, w = tid >> 6;
  int l15 = lane & 15, quad = lane >> 4;
  int bx = blockIdx.x, hh = blockIdx.y, z = blockIdx.z;
  int b = z >> 1, br = z & 1;
  int qh = br * 8 + hh;
  int kh = br * 4 + (hh >> 1);
  int vh = hh >> 1;

  const char* kbase_b = (const char*)(kp + ((size_t)(b * 8 + kh)) * T_SEQ * 128);
  const char* vbase_b = (const char*)(vt + ((size_t)(b * 4 + vh)) * 256 * T_SEQ);
  _Float16* pw = &Pt[w * 16 * 72];
  float sc = scaler[qh] * 0.08838834764831844f; // 1/sqrt(128)

  // staging lane constants
  int krow_l = lane >> 4;          // row within 4-row K chunk
  int kpc    = (lane & 15) << 4;   // byte col within 256B K row
  int vrow_l = lane >> 3;          // row within 8-row V chunk
  int vpc    = (lane & 7) << 4;    // byte col within 128B V row

  // wave w stages K rows 16w..16w+15 (4 chunks x 1KB) and V dims 32w..32w+31 per half
  auto stageK = [&](int kt1) {
    int ksr = kt1 * 64;
    char* dstb = Ks[kt1 & 1];
#pragma unroll
    for (int c2 = 0; c2 < 4; c2++) {
      int cc = w * 4 + c2;
      int row = cc * 4 + krow_l;
      const char* src = kbase_b + (((size_t)(ksr + row)) << 8) + (kpc ^ ((row & 7) << 4));
      GLD16(src, dstb + (cc << 10));
    }
  };
  auto stageV = [&](int kt1) {
    int ksb = kt1 * 128; // key-start byte offset within a V row
#pragma unroll
    for (int h = 0; h < 2; h++)
#pragma unroll
      for (int c2 = 0; c2 < 4; c2++) {
        int cc = w * 4 + c2;
        int d = h * 128 + cc * 8 + vrow_l;
        const char* src = vbase_b + (size_t)d * (T_SEQ * 2) + ksb + (vpc ^ (vrow_l << 4));
        GLD16(src, Vs[h] + (cc << 10));
      }
  };

  for (int half = 0; half < 2; half++) {
    int qt = half ? (31 - bx) : bx;
    int t0 = qt * 64;
    int tg = t0 + w * 16 + l15;  // this lane's query row (swapped layout)

    // Q fragments (B-operand: n = lane&15, k = quad*8+j); q in-place, row stride NQKV
    const _Float16* qbase = qkv + ((size_t)(b * T_SEQ + tg)) * NQKV + qh * 128;
    half8 qf[4];
#pragma unroll
    for (int kc = 0; kc < 4; kc++)
      qf[kc] = *(const half8*)(qbase + kc * 32 + quad * 8);

    // prologue: async-stage tile 0 (prev half's last barrier guarantees buffers free)
    stageK(0);
    stageV(0);
    __builtin_amdgcn_sched_barrier(0);

    float mrow = NEG_BIG, lrow = 0.f;          // per-lane: query = lane&15
    float rowscale = sc * logf((float)(tg + 1));
    f32x4 acc[16];
#pragma unroll
    for (int nb = 0; nb < 16; nb++) acc[nb] = (f32x4){0.f, 0.f, 0.f, 0.f};

    for (int kt = 0; kt <= qt; kt++) {
      int ks = kt * 64;
      bool notlast = (kt < qt);

      // (A) K(kt) ready; V(kt) stays in flight
      asm volatile("s_waitcnt vmcnt(8)" ::: "memory");
      __builtin_amdgcn_s_barrier();
      __builtin_amdgcn_sched_barrier(0);
      if (notlast) stageK(kt + 1);

      // (B) S^T = K Q^T from LDS (swizzled ds_read_b128); row=key, col=query
      const char* kbuf = Ks[kt & 1];
      f32x4 sv[4];
#pragma unroll
      for (int j = 0; j < 4; j++) {
        int row = j * 16 + l15;
        int sw = (row & 7) << 4;
        const char* kr = kbuf + (row << 8);
        half8 kf0 = *(const half8*)(kr + (((quad << 4) + 0) ^ sw));
        half8 kf1 = *(const half8*)(kr + (((quad << 4) + 64) ^ sw));
        half8 kf2 = *(const half8*)(kr + (((quad << 4) + 128) ^ sw));
        half8 kf3 = *(const half8*)(kr + (((quad << 4) + 192) ^ sw));
        f32x4 a = (f32x4){0.f, 0.f, 0.f, 0.f};
        a = __builtin_amdgcn_mfma_f32_16x16x32_f16(kf0, qf[0], a, 0, 0, 0);
        a = __builtin_amdgcn_mfma_f32_16x16x32_f16(kf1, qf[1], a, 0, 0, 0);
        a = __builtin_amdgcn_mfma_f32_16x16x32_f16(kf2, qf[2], a, 0, 0, 0);
        a = __builtin_amdgcn_mfma_f32_16x16x32_f16(kf3, qf[3], a, 0, 0, 0);
        sv[j] = a;
      }

      // (C) softmax — lane-local over 16 scores of query l15 (R3-exact, straight-line)
      bool diag = (kt == qt);
      float s_r[16];
      float mx = NEG_BIG;
#pragma unroll
      for (int j = 0; j < 4; j++)
#pragma unroll
        for (int r = 0; r < 4; r++) {
          float s = sv[j][r] * rowscale;
          if (diag) {
            int kg = ks + j * 16 + quad * 4 + r;
            if (kg > tg) s = NEG_BIG;
          }
          s_r[j * 4 + r] = s;
          mx = fmaxf(mx, s);
        }
      mx = fmaxf(mx, __shfl_xor(mx, 16, 64));
      mx = fmaxf(mx, __shfl_xor(mx, 32, 64));
      float mnew = fmaxf(mrow, mx);
      float alpha = __expf(mrow - mnew);
      float p[16];
      float rs = 0.f;
#pragma unroll
      for (int i = 0; i < 16; i++) {
        p[i] = __expf(s_r[i] - mnew);
        rs += p[i];
      }
      rs += __shfl_xor(rs, 16, 64);
      rs += __shfl_xor(rs, 32, 64);
      lrow = lrow * alpha + rs;
      mrow = mnew;
      // redistribute alpha: query q=quad*4+r lives at lane quad*16 + (quad*4+r) = 20*quad+r
      float at[4];
#pragma unroll
      for (int r = 0; r < 4; r++) at[r] = __shfl(alpha, quad * 20 + r, 64);
#pragma unroll
      for (int nb = 0; nb < 16; nb++)
#pragma unroll
        for (int r = 0; r < 4; r++) acc[nb][r] *= at[r];

      // (D) P -> LDS (packed b64) -> A-operand fragments (wave-private; no barrier)
#pragma unroll
      for (int j = 0; j < 4; j++) {
        half4 pk;
        pk[0] = (_Float16)p[j * 4 + 0];
        pk[1] = (_Float16)p[j * 4 + 1];
        pk[2] = (_Float16)p[j * 4 + 2];
        pk[3] = (_Float16)p[j * 4 + 3];
        *(half4*)&pw[l15 * 72 + j * 16 + quad * 4] = pk;
      }
      half8 pf0 = *(const half8*)&pw[l15 * 72 + quad * 8];
      half8 pf1 = *(const half8*)&pw[l15 * 72 + 32 + quad * 8];

      // (E) publish Vs: drain V(kt), keep K(kt+1) in flight
      if (notlast)
        asm volatile("s_waitcnt vmcnt(4)" ::: "memory");
      else
        asm volatile("s_waitcnt vmcnt(0)" ::: "memory");
      __builtin_amdgcn_s_barrier();
      __builtin_amdgcn_sched_barrier(0);

      // (F) O += P V from LDS (swizzled ds_read_b128)
#pragma unroll
      for (int h = 0; h < 2; h++) {
#pragma unroll
        for (int nbl = 0; nbl < 8; nbl++) {
          int row = nbl * 16 + l15;
          int sw = (row & 7) << 4;
          const char* vr = Vs[h] + (row << 7);
          half8 vf0 = *(const half8*)(vr + (((quad << 4) + 0) ^ sw));
          half8 vf1 = *(const half8*)(vr + (((quad << 4) + 64) ^ sw));
          int nb = h * 8 + nbl;
          acc[nb] = __builtin_amdgcn_mfma_f32_16x16x32_f16(pf0, vf0, acc[nb], 0, 0, 0);
          acc[nb] = __builtin_amdgcn_mfma_f32_16x16x32_f16(pf1, vf1, acc[nb], 0, 0, 0);
        }
      }

      // (G) Vs consumed by all waves -> prefetch V(kt+1)
      asm volatile("s_waitcnt lgkmcnt(0)" ::: "memory");
      __builtin_amdgcn_s_barrier();
      __builtin_amdgcn_sched_barrier(0);
      if (notlast) stageV(kt + 1);
    }

    // epilogue: divide by l (redistributed to acc domain); y1 -> f32, y2 -> fp16
    float linv = 1.0f / lrow;
    float lt[4];
#pragma unroll
    for (int r = 0; r < 4; r++) lt[r] = __shfl(linv, quad * 20 + r, 64);
#pragma unroll
    for (int r = 0; r < 4; r++) {
      int tr = t0 + w * 16 + quad * 4 + r;
      size_t base = ((size_t)(b * T_SEQ + tr)) * 2048 + hh * 256;
      if (br) {
#pragma unroll
        for (int nb = 0; nb < 16; nb++)
          y2out[base + nb * 16 + l15] = (_Float16)(acc[nb][r] * lt[r]);
      } else {
#pragma unroll
        for (int nb = 0; nb < 16; nb++)
          y1out[base + nb * 16 + l15] = acc[nb][r] * lt[r];
      }
    }
  }
}

// ---------------- out = y1 - lam * y2 (f32, in place on d_out) ----------------
__global__ __launch_bounds__(256) void combine(float* __restrict__ out,
                                               const _Float16* __restrict__ y2,
                                               const float* __restrict__ lq1,
                                               const float* __restrict__ lk1,
                                               const float* __restrict__ lq2,
                                               const float* __restrict__ lk2) {
  int lane = threadIdx.x & 63;
  float a = lq1[lane] * lk1[lane];
  float bb = lq2[lane] * lk2[lane];
#pragma unroll
  for (int m = 1; m < 64; m <<= 1) {
    a += __shfl_xor(a, m, 64);
    bb += __shfl_xor(bb, m, 64);
  }
  float lam = expf(a) - expf(bb) + 0.2f;

  size_t o = ((size_t)blockIdx.x * 256 + threadIdx.x) * 8;
  half8 yv = *(const half8*)(y2 + o);
  float4 a0 = *(float4*)(out + o);
  float4 a1 = *(float4*)(out + o + 4);
  a0.x -= lam * (float)yv[0];
  a0.y -= lam * (float)yv[1];
  a0.z -= lam * (float)yv[2];
  a0.w -= lam * (float)yv[3];
  a1.x -= lam * (float)yv[4];
  a1.y -= lam * (float)yv[5];
  a1.z -= lam * (float)yv[6];
  a1.w -= lam * (float)yv[7];
  *(float4*)(out + o) = a0;
  *(float4*)(out + o + 4) = a1;
}

extern "C" void kernel_launch(void* const* d_in, const int* in_sizes, int n_in,
                              void* d_out, int out_size, void* d_ws, size_t ws_size,
                              hipStream_t stream) {
  const float* x   = (const float*)d_in[0];
  const float* Wq  = (const float*)d_in[1];
  const float* Wk  = (const float*)d_in[2];
  const float* Wv  = (const float*)d_in[3];
  const float* lq1 = (const float*)d_in[4];
  const float* lk1 = (const float*)d_in[5];
  const float* lq2 = (const float*)d_in[6];
  const float* lk2 = (const float*)d_in[7];
  const float* scaler = (const float*)d_in[8];
  float* out = (float*)d_out;

  char* W = (char*)d_ws;
  // Workspace high-water 64 MiB (proven safe):
  // Phase 1 (until gemm done): xh [0,16.78M), wh [16.78,33.55M), qkvh [33.55,67.11M)
  // Phase 2 (after gemm, xh/wh dead): kp [0,8.39M), vtb [8.39,16.78M), y2h [16.78,33.55M)
  // RoPE tables live in d_out[0, 1.05MB) (free until attn writes y1 there).
  _Float16* xh   = (_Float16*)(W + 0);
  _Float16* wh   = (_Float16*)(W + 16777216);
  _Float16* qkvh = (_Float16*)(W + 33554432);
  _Float16* kph  = (_Float16*)(W + 0);
  _Float16* vtb  = (_Float16*)(W + 8388608);
  _Float16* y2h  = (_Float16*)(W + 16777216);
  float* cosT    = out;            // 2048*64 f32 = 0.52 MB
  float* sinT    = out + 131072;   // 0.52 MB (ends at 1.05 MB)

  build_rope<<<T_SEQ, 64, 0, stream>>>(cosT, sinT);
  cvt_xw<<<8192, 256, 0, stream>>>(x, Wq, Wk, Wv, xh, wh);
  gemm_nt<<<dim3(NQKV / 128, MROWS / 128), 256, 0, stream>>>(xh, wh, qkvh);
  postproc<<<dim3(256, 24), 256, 0, stream>>>(qkvh, cosT, sinT, kph);
  transpose_v<<<dim3(T_SEQ / 32, 256 / 32, BSZ * 4), dim3(32, 8), 0, stream>>>(qkvh, vtb);
  attn<<<dim3(16, 8, BSZ * 2), 256, 0, stream>>>(qkvh, kph, vtb, scaler, out, y2h);
  combine<<<4096, 256, 0, stream>>>(out, y2h, lq1, lk1, lq2, lk2);
}

// Round 8
// 314.906 us; speedup vs baseline: 1.1930x; 1.0047x over previous
//
#include <hip/hip_runtime.h>

// Fixed shapes. I/O f32 (proven R7). Intermediates fp16, f32 accum.
#define T_SEQ 2048
#define DMODEL 2048
#define BSZ 2
#define MROWS (BSZ * T_SEQ)   // 4096 tokens
#define NQKV 4096             // 2048 q | 1024 k | 1024 v
#define NEG_BIG (-1e30f)

typedef __attribute__((ext_vector_type(8))) _Float16 half8;  // 16B, 4 VGPRs
typedef __attribute__((ext_vector_type(4))) _Float16 half4;  // 8B
typedef __attribute__((ext_vector_type(4))) float f32x4;     // MFMA acc

// async global->LDS, 16B per lane (dest = wave-uniform base + lane*16, linear)
typedef const __attribute__((address_space(1))) unsigned int* gas_ptr;
typedef __attribute__((address_space(3))) unsigned int* las_ptr;
#define GLD16(g, l) __builtin_amdgcn_global_load_lds((gas_ptr)(g), (las_ptr)(l), 16, 0, 0)

__device__ __forceinline__ unsigned short f2bf(float f) {
  unsigned u = __float_as_uint(f);
  unsigned r = (u + 0x7fffu + ((u >> 16) & 1u)) >> 16; // RNE
  return (unsigned short)r;
}
__device__ __forceinline__ float bf2f(unsigned short h) {
  return __uint_as_float(((unsigned)h) << 16);
}

// ---------------- prep: x/W (f32)->fp16 + RoPE tables (merged; verified R7-safe) ----------------
// bid < 8192: cvt (4096 x-blocks, 4096 W-blocks). bid >= 8192: rope row t = bid-8192.
__global__ __launch_bounds__(256) void prep(const float* __restrict__ x,
                                            const float* __restrict__ Wq,
                                            const float* __restrict__ Wk,
                                            const float* __restrict__ Wv,
                                            _Float16* __restrict__ xh,
                                            _Float16* __restrict__ wh,
                                            float* __restrict__ cosT,
                                            float* __restrict__ sinT) {
  int bid = blockIdx.x;
  if (bid < 8192) {
    size_t o = ((size_t)(bid & 4095) * 256 + threadIdx.x) * 8;
    const float* src;
    _Float16* dst;
    if (bid < 4096) {
      src = x + o;
      dst = xh + o;
    } else {
      int row = (int)(o >> 11), col = (int)(o & 2047);
      src = ((row < 2048) ? (Wq + (size_t)row * 2048)
            : (row < 3072) ? (Wk + (size_t)(row - 2048) * 2048)
                           : (Wv + (size_t)(row - 3072) * 2048)) + col;
      dst = wh + o;
    }
    float4 v0 = *(const float4*)(src);
    float4 v1 = *(const float4*)(src + 4);
    half8 r;
    r[0] = (_Float16)v0.x; r[1] = (_Float16)v0.y; r[2] = (_Float16)v0.z; r[3] = (_Float16)v0.w;
    r[4] = (_Float16)v1.x; r[5] = (_Float16)v1.y; r[6] = (_Float16)v1.z; r[7] = (_Float16)v1.w;
    *(half8*)(dst) = r;
  } else {
    int t = bid - 8192;    // 0..2047
    int i = threadIdx.x;   // use lanes 0..63
    if (i < 64) {
      float inv = (float)pow(10000.0, -((double)(2 * i)) / 128.0);
      float fr = (float)t * inv;
      cosT[t * 64 + i] = bf2f(f2bf(cosf(fr)));
      sinT[t * 64 + i] = bf2f(f2bf(sinf(fr)));
    }
  }
}

// ---------------- NT GEMM v2: qkv[M,4096] = xh[M,K] * wh[4096,K]^T (proven R3) ----------------
__global__ __launch_bounds__(256) void gemm_nt(const _Float16* __restrict__ A,
                                               const _Float16* __restrict__ Bw,
                                               _Float16* __restrict__ C) {
  const int K = DMODEL, N = NQKV;
  __shared__ __align__(16) char As[2][128 * 128];  // 16KB per buf (128 rows x 128B)
  __shared__ __align__(16) char Bs[2][128 * 128];  // total LDS 64KB -> 2 blocks/CU
  int tid = threadIdx.x;
  int lane = tid & 63, w = tid >> 6;
  int wm = w >> 1, wn = w & 1;
  int l15 = lane & 15, quad = lane >> 4;
  int bm = blockIdx.y, bn = blockIdx.x;

  const char* Aab = (const char*)(A + (size_t)(bm * 128) * K);
  const char* Bab = (const char*)(Bw + (size_t)(bn * 128) * K);
  int srow = lane >> 3;                      // 0..7: row within 8-row chunk
  int scol = ((lane & 7) ^ srow) << 4;       // pre-swizzled byte col within 128B row

  // wave w stages rows [w*32, w*32+32): 4 chunks x 1KB per matrix
  auto stage = [&](int t) {
    int buf = t & 1;
    size_t kb = (size_t)t << 7;              // t*64 halves = t*128 bytes along K
#pragma unroll
    for (int g = 0; g < 4; g++) {
      int row = w * 32 + g * 8 + srow;
      GLD16(Aab + (size_t)row * (K * 2) + kb + scol, &As[buf][w * 4096 + g * 1024]);
    }
#pragma unroll
    for (int g = 0; g < 4; g++) {
      int row = w * 32 + g * 8 + srow;
      GLD16(Bab + (size_t)row * (K * 2) + kb + scol, &Bs[buf][w * 4096 + g * 1024]);
    }
  };

  f32x4 acc[4][4];
#pragma unroll
  for (int i = 0; i < 4; i++)
#pragma unroll
    for (int j = 0; j < 4; j++) acc[i][j] = (f32x4){0.f, 0.f, 0.f, 0.f};

  stage(0);
  for (int t = 0; t < 32; t++) {
    if (t < 31) {
      stage(t + 1);
      asm volatile("s_waitcnt vmcnt(8)" ::: "memory");  // t's 8 done; t+1's 8 in flight
    } else {
      asm volatile("s_waitcnt vmcnt(0)" ::: "memory");
    }
    __builtin_amdgcn_s_barrier();
    __builtin_amdgcn_sched_barrier(0);

    const char* ab = As[t & 1];
    const char* bb = Bs[t & 1];
#pragma unroll
    for (int kc = 0; kc < 2; kc++) {
      half8 af[4], bfr[4];
#pragma unroll
      for (int i = 0; i < 4; i++) {
        int row = wm * 64 + i * 16 + l15;
        af[i] = *(const half8*)(ab + row * 128 + ((kc * 64 + quad * 16) ^ ((row & 7) << 4)));
      }
#pragma unroll
      for (int j = 0; j < 4; j++) {
        int row = wn * 64 + j * 16 + l15;
        bfr[j] = *(const half8*)(bb + row * 128 + ((kc * 64 + quad * 16) ^ ((row & 7) << 4)));
      }
#pragma unroll
      for (int i = 0; i < 4; i++)
#pragma unroll
        for (int j = 0; j < 4; j++)
          acc[i][j] = __builtin_amdgcn_mfma_f32_16x16x32_f16(af[i], bfr[j], acc[i][j], 0, 0, 0);
    }

    asm volatile("s_waitcnt lgkmcnt(0)" ::: "memory");  // this wave's ds_reads done
    __builtin_amdgcn_s_barrier();                       // buf t&1 free for stage(t+2)
    __builtin_amdgcn_sched_barrier(0);
  }

#pragma unroll
  for (int i = 0; i < 4; i++)
#pragma unroll
    for (int j = 0; j < 4; j++)
#pragma unroll
      for (int r = 0; r < 4; r++) {
        int row = bm * 128 + wm * 64 + i * 16 + quad * 4 + r;
        int col = bn * 128 + wn * 64 + j * 16 + l15;
        C[(size_t)row * N + col] = (_Float16)acc[i][j][r];
      }
}

// ---------------- mid: RMSNorm+RoPE (proven R4) + V-transpose, merged ----------------
// bid < 6144: postproc (xb = bid&255, h = bid>>8). bid >= 6144: transpose (flat 4096 blocks).
__global__ __launch_bounds__(256) void mid(_Float16* __restrict__ qkv,
                                           const float* __restrict__ cosT,
                                           const float* __restrict__ sinT,
                                           _Float16* __restrict__ kp,
                                           _Float16* __restrict__ vt) {
  __shared__ _Float16 tile[32][33];
  int bid = blockIdx.x;
  if (bid < 6144) {
    int tid = threadIdx.x, lane = tid & 63, w = tid >> 6;
    int h = bid >> 8;                                   // 0..23
    int tkn = (bid & 255) * 16 + w * 4 + (lane >> 4);   // 0..4095
    int b = tkn >> 11, t = tkn & 2047;
    int l15 = lane & 15;
    int col0 = (h < 16) ? (h * 128) : (2048 + (h - 16) * 128);
    size_t base = (size_t)tkn * NQKV + col0 + l15 * 8;

    half8 v = *(const half8*)(qkv + base);
    float xf[8];
    float ss = 0.f;
#pragma unroll
    for (int j = 0; j < 8; j++) { xf[j] = (float)v[j]; ss += xf[j] * xf[j]; }
    ss += __shfl_xor(ss, 1, 64);
    ss += __shfl_xor(ss, 2, 64);
    ss += __shfl_xor(ss, 4, 64);
    ss += __shfl_xor(ss, 8, 64);
    float rn = rsqrtf(ss * (1.0f / 128.0f) + 1.1920929e-7f);

    const float* cb = cosT + t * 64 + (lane & 7) * 8;
    const float* sb = sinT + t * 64 + (lane & 7) * 8;
    float4 c0 = *(const float4*)cb, c1 = *(const float4*)(cb + 4);
    float4 s0 = *(const float4*)sb, s1 = *(const float4*)(sb + 4);
    float cc[8] = {c0.x, c0.y, c0.z, c0.w, c1.x, c1.y, c1.z, c1.w};
    float sn[8] = {s0.x, s0.y, s0.z, s0.w, s1.x, s1.y, s1.z, s1.w};
    float sgn = (lane & 8) ? -1.f : 1.f;

    half8 o;
#pragma unroll
    for (int j = 0; j < 8; j++) {
      float xn = xf[j] * rn;
      float xp = __shfl_xor(xn, 8, 64);   // partner dim d +/- 64
      o[j] = (_Float16)(xn * cc[j] + sgn * xp * sn[j]);
    }
    if (h < 16)
      *(half8*)(qkv + base) = o;
    else
      *(half8*)(kp + (((size_t)(b * 8 + (h - 16))) * T_SEQ + t) * 128 + l15 * 8) = o;
  } else {
    int tb = bid - 6144;                       // 0..4095 (was grid 64x8x8)
    int t0 = (tb & 63) * 32, d0 = ((tb >> 6) & 7) * 32;
    int bz = tb >> 9;
    int b = bz >> 2, vh = bz & 3;
    int tx = threadIdx.x & 31, ty = threadIdx.x >> 5;
#pragma unroll
    for (int i = 0; i < 4; i++) {
      int t = t0 + ty + i * 8;
      tile[ty + i * 8][tx] = qkv[((size_t)(b * T_SEQ + t)) * NQKV + 3072 + vh * 256 + d0 + tx];
    }
    __syncthreads();
#pragma unroll
    for (int i = 0; i < 4; i++) {
      int d = d0 + ty + i * 8;
      vt[(((size_t)(b * 4 + vh)) * 256 + d) * T_SEQ + t0 + tx] = tile[tx][ty + i * 8];
    }
  }
}

// ---------------- causal flash attention v9 = R6-proven structure + exp2 softmax only ----------------
// R7 post-mortem: the in-register permlane P redistribution failed correctness (absmax 4.3,
// lane-misdelivery signature — unverifiable swap-direction semantics). REVERTED to the R6
// LDS P roundtrip. Kept only exp2-domain softmax (straight-line, unconditional rescale;
// numerically equivalent, R4 counters proved the VALU saving; the R4 branch stays banned).
__global__ __launch_bounds__(256) void attn(const _Float16* __restrict__ qkv,
                                            const _Float16* __restrict__ kp,
                                            const _Float16* __restrict__ vt,
                                            const float* __restrict__ scaler,
                                            float* __restrict__ y1out,
                                            _Float16* __restrict__ y2out) {
  __shared__ __align__(16) char Ks[2][64 * 256];   // 32 KB: K tile, dbuf (256B rows, swizzled)
  __shared__ __align__(16) char Vs[2][128 * 128];  // 32 KB: V^T halves (128B rows, swizzled)
  __shared__ _Float16 Pt[4 * 16 * 72];             // 9 KB: per-wave P (A-operand layout)
  // total LDS 74752 B -> 2 blocks/CU

  int tid = threadIdx.x, lane = tid & 63, w = tid >> 6;
  int l15 = lane & 15, quad = lane >> 4;
  int bx = blockIdx.x, hh = blockIdx.y, z = blockIdx.z;
  int b = z >> 1, br = z & 1;
  int qh = br * 8 + hh;
  int kh = br * 4 + (hh >> 1);
  int vh = hh >> 1;

  const char* kbase_b = (const char*)(kp + ((size_t)(b * 8 + kh)) * T_SEQ * 128);
  const char* vbase_b = (const char*)(vt + ((size_t)(b * 4 + vh)) * 256 * T_SEQ);
  _Float16* pw = &Pt[w * 16 * 72];
  float sc = scaler[qh] * 0.08838834764831844f; // 1/sqrt(128)

  // staging lane constants
  int krow_l = lane >> 4;          // row within 4-row K chunk
  int kpc    = (lane & 15) << 4;   // byte col within 256B K row
  int vrow_l = lane >> 3;          // row within 8-row V chunk
  int vpc    = (lane & 7) << 4;    // byte col within 128B V row

  // wave w stages K rows 16w..16w+15 (4 chunks x 1KB) and V dims 32w..32w+31 per half
  auto stageK = [&](int kt1) {
    int ksr = kt1 * 64;
    char* dstb = Ks[kt1 & 1];
#pragma unroll
    for (int c2 = 0; c2 < 4; c2++) {
      int cc = w * 4 + c2;
      int row = cc * 4 + krow_l;
      const char* src = kbase_b + (((size_t)(ksr + row)) << 8) + (kpc ^ ((row & 7) << 4));
      GLD16(src, dstb + (cc << 10));
    }
  };
  auto stageV = [&](int kt1) {
    int ksb = kt1 * 128; // key-start byte offset within a V row
#pragma unroll
    for (int h = 0; h < 2; h++)
#pragma unroll
      for (int c2 = 0; c2 < 4; c2++) {
        int cc = w * 4 + c2;
        int d = h * 128 + cc * 8 + vrow_l;
        const char* src = vbase_b + (size_t)d * (T_SEQ * 2) + ksb + (vpc ^ (vrow_l << 4));
        GLD16(src, Vs[h] + (cc << 10));
      }
  };

  for (int half = 0; half < 2; half++) {
    int qt = half ? (31 - bx) : bx;
    int t0 = qt * 64;
    int tg = t0 + w * 16 + l15;  // this lane's query row (swapped layout)

    // Q fragments (B-operand: n = lane&15, k = quad*8+j); q in-place, row stride NQKV
    const _Float16* qbase = qkv + ((size_t)(b * T_SEQ + tg)) * NQKV + qh * 128;
    half8 qf[4];
#pragma unroll
    for (int kc = 0; kc < 4; kc++)
      qf[kc] = *(const half8*)(qbase + kc * 32 + quad * 8);

    // prologue: async-stage tile 0 (prev half's last barrier guarantees buffers free)
    stageK(0);
    stageV(0);
    __builtin_amdgcn_sched_barrier(0);

    float mrow = NEG_BIG, lrow = 0.f;          // per-lane: query = lane&15 (log2 domain)
    float rowscale = sc * logf((float)(tg + 1)) * 1.44269504f;  // fold log2(e)
    f32x4 acc[16];
#pragma unroll
    for (int nb = 0; nb < 16; nb++) acc[nb] = (f32x4){0.f, 0.f, 0.f, 0.f};

    for (int kt = 0; kt <= qt; kt++) {
      int ks = kt * 64;
      bool notlast = (kt < qt);

      // (A) K(kt) ready; V(kt) stays in flight
      asm volatile("s_waitcnt vmcnt(8)" ::: "memory");
      __builtin_amdgcn_s_barrier();
      __builtin_amdgcn_sched_barrier(0);
      if (notlast) stageK(kt + 1);

      // (B) S^T = K Q^T from LDS (swizzled ds_read_b128); row=key, col=query
      const char* kbuf = Ks[kt & 1];
      f32x4 sv[4];
#pragma unroll
      for (int j = 0; j < 4; j++) {
        int row = j * 16 + l15;
        int sw = (row & 7) << 4;
        const char* kr = kbuf + (row << 8);
        half8 kf0 = *(const half8*)(kr + (((quad << 4) + 0) ^ sw));
        half8 kf1 = *(const half8*)(kr + (((quad << 4) + 64) ^ sw));
        half8 kf2 = *(const half8*)(kr + (((quad << 4) + 128) ^ sw));
        half8 kf3 = *(const half8*)(kr + (((quad << 4) + 192) ^ sw));
        f32x4 a = (f32x4){0.f, 0.f, 0.f, 0.f};
        a = __builtin_amdgcn_mfma_f32_16x16x32_f16(kf0, qf[0], a, 0, 0, 0);
        a = __builtin_amdgcn_mfma_f32_16x16x32_f16(kf1, qf[1], a, 0, 0, 0);
        a = __builtin_amdgcn_mfma_f32_16x16x32_f16(kf2, qf[2], a, 0, 0, 0);
        a = __builtin_amdgcn_mfma_f32_16x16x32_f16(kf3, qf[3], a, 0, 0, 0);
        sv[j] = a;
      }

      // (C) softmax — lane-local over 16 scores of query l15 (log2 domain, straight-line)
      bool diag = (kt == qt);
      float s_r[16];
      float mx = NEG_BIG;
#pragma unroll
      for (int j = 0; j < 4; j++)
#pragma unroll
        for (int r = 0; r < 4; r++) {
          float s = sv[j][r] * rowscale;
          if (diag) {
            int kg = ks + j * 16 + quad * 4 + r;
            if (kg > tg) s = NEG_BIG;
          }
          s_r[j * 4 + r] = s;
          mx = fmaxf(mx, s);
        }
      mx = fmaxf(mx, __shfl_xor(mx, 16, 64));
      mx = fmaxf(mx, __shfl_xor(mx, 32, 64));
      float mnew = fmaxf(mrow, mx);
      float alpha = __builtin_amdgcn_exp2f(mrow - mnew);
      float p[16];
      float rs = 0.f;
#pragma unroll
      for (int i = 0; i < 16; i++) {
        p[i] = __builtin_amdgcn_exp2f(s_r[i] - mnew);
        rs += p[i];
      }
      rs += __shfl_xor(rs, 16, 64);
      rs += __shfl_xor(rs, 32, 64);
      lrow = lrow * alpha + rs;
      mrow = mnew;
      // redistribute alpha: query q=quad*4+r lives at lane quad*16 + (quad*4+r) = 20*quad+r
      float at[4];
#pragma unroll
      for (int r = 0; r < 4; r++) at[r] = __shfl(alpha, quad * 20 + r, 64);
#pragma unroll
      for (int nb = 0; nb < 16; nb++)
#pragma unroll
        for (int r = 0; r < 4; r++) acc[nb][r] *= at[r];

      // (D) P -> LDS (packed b64) -> A-operand fragments (wave-private; no barrier)
#pragma unroll
      for (int j = 0; j < 4; j++) {
        half4 pk;
        pk[0] = (_Float16)p[j * 4 + 0];
        pk[1] = (_Float16)p[j * 4 + 1];
        pk[2] = (_Float16)p[j * 4 + 2];
        pk[3] = (_Float16)p[j * 4 + 3];
        *(half4*)&pw[l15 * 72 + j * 16 + quad * 4] = pk;
      }
      half8 pf0 = *(const half8*)&pw[l15 * 72 + quad * 8];
      half8 pf1 = *(const half8*)&pw[l15 * 72 + 32 + quad * 8];

      // (E) publish Vs: drain V(kt), keep K(kt+1) in flight
      if (notlast)
        asm volatile("s_waitcnt vmcnt(4)" ::: "memory");
      else
        asm volatile("s_waitcnt vmcnt(0)" ::: "memory");
      __builtin_amdgcn_s_barrier();
      __builtin_amdgcn_sched_barrier(0);

      // (F) O += P V from LDS (swizzled ds_read_b128)
#pragma unroll
      for (int h = 0; h < 2; h++) {
#pragma unroll
        for (int nbl = 0; nbl < 8; nbl++) {
          int row = nbl * 16 + l15;
          int sw = (row & 7) << 4;
          const char* vr = Vs[h] + (row << 7);
          half8 vf0 = *(const half8*)(vr + (((quad << 4) + 0) ^ sw));
          half8 vf1 = *(const half8*)(vr + (((quad << 4) + 64) ^ sw));
          int nb = h * 8 + nbl;
          acc[nb] = __builtin_amdgcn_mfma_f32_16x16x32_f16(pf0, vf0, acc[nb], 0, 0, 0);
          acc[nb] = __builtin_amdgcn_mfma_f32_16x16x32_f16(pf1, vf1, acc[nb], 0, 0, 0);
        }
      }

      // (G) Vs consumed by all waves -> prefetch V(kt+1)
      asm volatile("s_waitcnt lgkmcnt(0)" ::: "memory");
      __builtin_amdgcn_s_barrier();
      __builtin_amdgcn_sched_barrier(0);
      if (notlast) stageV(kt + 1);
    }

    // epilogue: divide by l (redistributed to acc domain); y1 -> f32, y2 -> fp16
    float linv = 1.0f / lrow;
    float lt[4];
#pragma unroll
    for (int r = 0; r < 4; r++) lt[r] = __shfl(linv, quad * 20 + r, 64);
#pragma unroll
    for (int r = 0; r < 4; r++) {
      int tr = t0 + w * 16 + quad * 4 + r;
      size_t base = ((size_t)(b * T_SEQ + tr)) * 2048 + hh * 256;
      if (br) {
#pragma unroll
        for (int nb = 0; nb < 16; nb++)
          y2out[base + nb * 16 + l15] = (_Float16)(acc[nb][r] * lt[r]);
      } else {
#pragma unroll
        for (int nb = 0; nb < 16; nb++)
          y1out[base + nb * 16 + l15] = acc[nb][r] * lt[r];
      }
    }
  }
}

// ---------------- out = y1 - lam * y2 (f32, in place on d_out) ----------------
__global__ __launch_bounds__(256) void combine(float* __restrict__ out,
                                               const _Float16* __restrict__ y2,
                                               const float* __restrict__ lq1,
                                               const float* __restrict__ lk1,
                                               const float* __restrict__ lq2,
                                               const float* __restrict__ lk2) {
  int lane = threadIdx.x & 63;
  float a = lq1[lane] * lk1[lane];
  float bb = lq2[lane] * lk2[lane];
#pragma unroll
  for (int m = 1; m < 64; m <<= 1) {
    a += __shfl_xor(a, m, 64);
    bb += __shfl_xor(bb, m, 64);
  }
  float lam = expf(a) - expf(bb) + 0.2f;

  size_t o = ((size_t)blockIdx.x * 256 + threadIdx.x) * 8;
  half8 yv = *(const half8*)(y2 + o);
  float4 a0 = *(float4*)(out + o);
  float4 a1 = *(float4*)(out + o + 4);
  a0.x -= lam * (float)yv[0];
  a0.y -= lam * (float)yv[1];
  a0.z -= lam * (float)yv[2];
  a0.w -= lam * (float)yv[3];
  a1.x -= lam * (float)yv[4];
  a1.y -= lam * (float)yv[5];
  a1.z -= lam * (float)yv[6];
  a1.w -= lam * (float)yv[7];
  *(float4*)(out + o) = a0;
  *(float4*)(out + o + 4) = a1;
}

extern "C" void kernel_launch(void* const* d_in, const int* in_sizes, int n_in,
                              void* d_out, int out_size, void* d_ws, size_t ws_size,
                              hipStream_t stream) {
  const float* x   = (const float*)d_in[0];
  const float* Wq  = (const float*)d_in[1];
  const float* Wk  = (const float*)d_in[2];
  const float* Wv  = (const float*)d_in[3];
  const float* lq1 = (const float*)d_in[4];
  const float* lk1 = (const float*)d_in[5];
  const float* lq2 = (const float*)d_in[6];
  const float* lk2 = (const float*)d_in[7];
  const float* scaler = (const float*)d_in[8];
  float* out = (float*)d_out;

  char* W = (char*)d_ws;
  // Workspace high-water 64 MiB (proven safe):
  // Phase 1 (until gemm done): xh [0,16.78M), wh [16.78,33.55M), qkvh [33.55,67.11M)
  // Phase 2 (after gemm, xh/wh dead): kp [0,8.39M), vtb [8.39,16.78M), y2h [16.78,33.55M)
  // RoPE tables live in d_out[0, 1.05MB) (free until attn writes y1 there).
  _Float16* xh   = (_Float16*)(W + 0);
  _Float16* wh   = (_Float16*)(W + 16777216);
  _Float16* qkvh = (_Float16*)(W + 33554432);
  _Float16* kph  = (_Float16*)(W + 0);
  _Float16* vtb  = (_Float16*)(W + 8388608);
  _Float16* y2h  = (_Float16*)(W + 16777216);
  float* cosT    = out;            // 2048*64 f32 = 0.52 MB
  float* sinT    = out + 131072;   // 0.52 MB (ends at 1.05 MB)

  prep<<<10240, 256, 0, stream>>>(x, Wq, Wk, Wv, xh, wh, cosT, sinT);
  gemm_nt<<<dim3(NQKV / 128, MROWS / 128), 256, 0, stream>>>(xh, wh, qkvh);
  mid<<<10240, 256, 0, stream>>>(qkvh, cosT, sinT, kph, vtb);
  attn<<<dim3(16, 8, BSZ * 2), 256, 0, stream>>>(qkvh, kph, vtb, scaler, out, y2h);
  combine<<<4096, 256, 0, stream>>>(out, y2h, lq1, lk1, lq2, lk2);
}

// Round 9
// 313.481 us; speedup vs baseline: 1.1984x; 1.0045x over previous
//
#include <hip/hip_runtime.h>

// Fixed shapes. I/O f32 (proven R7). Intermediates fp16, f32 accum.
#define T_SEQ 2048
#define DMODEL 2048
#define BSZ 2
#define MROWS (BSZ * T_SEQ)   // 4096 tokens
#define NQKV 4096             // 2048 q | 1024 k | 1024 v
#define NEG_BIG (-1e30f)

typedef __attribute__((ext_vector_type(8))) _Float16 half8;  // 16B, 4 VGPRs
typedef __attribute__((ext_vector_type(4))) _Float16 half4;  // 8B
typedef __attribute__((ext_vector_type(4))) float f32x4;     // MFMA acc

// async global->LDS, 16B per lane (dest = wave-uniform base + lane*16, linear)
typedef const __attribute__((address_space(1))) unsigned int* gas_ptr;
typedef __attribute__((address_space(3))) unsigned int* las_ptr;
#define GLD16(g, l) __builtin_amdgcn_global_load_lds((gas_ptr)(g), (las_ptr)(l), 16, 0, 0)

__device__ __forceinline__ unsigned short f2bf(float f) {
  unsigned u = __float_as_uint(f);
  unsigned r = (u + 0x7fffu + ((u >> 16) & 1u)) >> 16; // RNE
  return (unsigned short)r;
}
__device__ __forceinline__ float bf2f(unsigned short h) {
  return __uint_as_float(((unsigned)h) << 16);
}

// ---------------- prep: x/W (f32)->fp16 + RoPE tables (merged; proven R8) ----------------
__global__ __launch_bounds__(256) void prep(const float* __restrict__ x,
                                            const float* __restrict__ Wq,
                                            const float* __restrict__ Wk,
                                            const float* __restrict__ Wv,
                                            _Float16* __restrict__ xh,
                                            _Float16* __restrict__ wh,
                                            float* __restrict__ cosT,
                                            float* __restrict__ sinT) {
  int bid = blockIdx.x;
  if (bid < 8192) {
    size_t o = ((size_t)(bid & 4095) * 256 + threadIdx.x) * 8;
    const float* src;
    _Float16* dst;
    if (bid < 4096) {
      src = x + o;
      dst = xh + o;
    } else {
      int row = (int)(o >> 11), col = (int)(o & 2047);
      src = ((row < 2048) ? (Wq + (size_t)row * 2048)
            : (row < 3072) ? (Wk + (size_t)(row - 2048) * 2048)
                           : (Wv + (size_t)(row - 3072) * 2048)) + col;
      dst = wh + o;
    }
    float4 v0 = *(const float4*)(src);
    float4 v1 = *(const float4*)(src + 4);
    half8 r;
    r[0] = (_Float16)v0.x; r[1] = (_Float16)v0.y; r[2] = (_Float16)v0.z; r[3] = (_Float16)v0.w;
    r[4] = (_Float16)v1.x; r[5] = (_Float16)v1.y; r[6] = (_Float16)v1.z; r[7] = (_Float16)v1.w;
    *(half8*)(dst) = r;
  } else {
    int t = bid - 8192;    // 0..2047
    int i = threadIdx.x;   // use lanes 0..63
    if (i < 64) {
      float inv = (float)pow(10000.0, -((double)(2 * i)) / 128.0);
      float fr = (float)t * inv;
      cosT[t * 64 + i] = bf2f(f2bf(cosf(fr)));
      sinT[t * 64 + i] = bf2f(f2bf(sinf(fr)));
    }
  }
}

// ---------------- NT GEMM v2: qkv[M,4096] = xh[M,K] * wh[4096,K]^T (proven R3) ----------------
__global__ __launch_bounds__(256) void gemm_nt(const _Float16* __restrict__ A,
                                               const _Float16* __restrict__ Bw,
                                               _Float16* __restrict__ C) {
  const int K = DMODEL, N = NQKV;
  __shared__ __align__(16) char As[2][128 * 128];  // 16KB per buf (128 rows x 128B)
  __shared__ __align__(16) char Bs[2][128 * 128];  // total LDS 64KB -> 2 blocks/CU
  int tid = threadIdx.x;
  int lane = tid & 63, w = tid >> 6;
  int wm = w >> 1, wn = w & 1;
  int l15 = lane & 15, quad = lane >> 4;
  int bm = blockIdx.y, bn = blockIdx.x;

  const char* Aab = (const char*)(A + (size_t)(bm * 128) * K);
  const char* Bab = (const char*)(Bw + (size_t)(bn * 128) * K);
  int srow = lane >> 3;                      // 0..7: row within 8-row chunk
  int scol = ((lane & 7) ^ srow) << 4;       // pre-swizzled byte col within 128B row

  // wave w stages rows [w*32, w*32+32): 4 chunks x 1KB per matrix
  auto stage = [&](int t) {
    int buf = t & 1;
    size_t kb = (size_t)t << 7;              // t*64 halves = t*128 bytes along K
#pragma unroll
    for (int g = 0; g < 4; g++) {
      int row = w * 32 + g * 8 + srow;
      GLD16(Aab + (size_t)row * (K * 2) + kb + scol, &As[buf][w * 4096 + g * 1024]);
    }
#pragma unroll
    for (int g = 0; g < 4; g++) {
      int row = w * 32 + g * 8 + srow;
      GLD16(Bab + (size_t)row * (K * 2) + kb + scol, &Bs[buf][w * 4096 + g * 1024]);
    }
  };

  f32x4 acc[4][4];
#pragma unroll
  for (int i = 0; i < 4; i++)
#pragma unroll
    for (int j = 0; j < 4; j++) acc[i][j] = (f32x4){0.f, 0.f, 0.f, 0.f};

  stage(0);
  for (int t = 0; t < 32; t++) {
    if (t < 31) {
      stage(t + 1);
      asm volatile("s_waitcnt vmcnt(8)" ::: "memory");  // t's 8 done; t+1's 8 in flight
    } else {
      asm volatile("s_waitcnt vmcnt(0)" ::: "memory");
    }
    __builtin_amdgcn_s_barrier();
    __builtin_amdgcn_sched_barrier(0);

    const char* ab = As[t & 1];
    const char* bb = Bs[t & 1];
#pragma unroll
    for (int kc = 0; kc < 2; kc++) {
      half8 af[4], bfr[4];
#pragma unroll
      for (int i = 0; i < 4; i++) {
        int row = wm * 64 + i * 16 + l15;
        af[i] = *(const half8*)(ab + row * 128 + ((kc * 64 + quad * 16) ^ ((row & 7) << 4)));
      }
#pragma unroll
      for (int j = 0; j < 4; j++) {
        int row = wn * 64 + j * 16 + l15;
        bfr[j] = *(const half8*)(bb + row * 128 + ((kc * 64 + quad * 16) ^ ((row & 7) << 4)));
      }
#pragma unroll
      for (int i = 0; i < 4; i++)
#pragma unroll
        for (int j = 0; j < 4; j++)
          acc[i][j] = __builtin_amdgcn_mfma_f32_16x16x32_f16(af[i], bfr[j], acc[i][j], 0, 0, 0);
    }

    asm volatile("s_waitcnt lgkmcnt(0)" ::: "memory");  // this wave's ds_reads done
    __builtin_amdgcn_s_barrier();                       // buf t&1 free for stage(t+2)
    __builtin_amdgcn_sched_barrier(0);
  }

#pragma unroll
  for (int i = 0; i < 4; i++)
#pragma unroll
    for (int j = 0; j < 4; j++)
#pragma unroll
      for (int r = 0; r < 4; r++) {
        int row = bm * 128 + wm * 64 + i * 16 + quad * 4 + r;
        int col = bn * 128 + wn * 64 + j * 16 + l15;
        C[(size_t)row * N + col] = (_Float16)acc[i][j][r];
      }
}

// ---------------- mid: RMSNorm+RoPE (proven R4) + V-transpose, merged (proven R8) ----------------
__global__ __launch_bounds__(256) void mid(_Float16* __restrict__ qkv,
                                           const float* __restrict__ cosT,
                                           const float* __restrict__ sinT,
                                           _Float16* __restrict__ kp,
                                           _Float16* __restrict__ vt) {
  __shared__ _Float16 tile[32][33];
  int bid = blockIdx.x;
  if (bid < 6144) {
    int tid = threadIdx.x, lane = tid & 63, w = tid >> 6;
    int h = bid >> 8;                                   // 0..23
    int tkn = (bid & 255) * 16 + w * 4 + (lane >> 4);   // 0..4095
    int b = tkn >> 11, t = tkn & 2047;
    int l15 = lane & 15;
    int col0 = (h < 16) ? (h * 128) : (2048 + (h - 16) * 128);
    size_t base = (size_t)tkn * NQKV + col0 + l15 * 8;

    half8 v = *(const half8*)(qkv + base);
    float xf[8];
    float ss = 0.f;
#pragma unroll
    for (int j = 0; j < 8; j++) { xf[j] = (float)v[j]; ss += xf[j] * xf[j]; }
    ss += __shfl_xor(ss, 1, 64);
    ss += __shfl_xor(ss, 2, 64);
    ss += __shfl_xor(ss, 4, 64);
    ss += __shfl_xor(ss, 8, 64);
    float rn = rsqrtf(ss * (1.0f / 128.0f) + 1.1920929e-7f);

    const float* cb = cosT + t * 64 + (lane & 7) * 8;
    const float* sb = sinT + t * 64 + (lane & 7) * 8;
    float4 c0 = *(const float4*)cb, c1 = *(const float4*)(cb + 4);
    float4 s0 = *(const float4*)sb, s1 = *(const float4*)(sb + 4);
    float cc[8] = {c0.x, c0.y, c0.z, c0.w, c1.x, c1.y, c1.z, c1.w};
    float sn[8] = {s0.x, s0.y, s0.z, s0.w, s1.x, s1.y, s1.z, s1.w};
    float sgn = (lane & 8) ? -1.f : 1.f;

    half8 o;
#pragma unroll
    for (int j = 0; j < 8; j++) {
      float xn = xf[j] * rn;
      float xp = __shfl_xor(xn, 8, 64);   // partner dim d +/- 64
      o[j] = (_Float16)(xn * cc[j] + sgn * xp * sn[j]);
    }
    if (h < 16)
      *(half8*)(qkv + base) = o;
    else
      *(half8*)(kp + (((size_t)(b * 8 + (h - 16))) * T_SEQ + t) * 128 + l15 * 8) = o;
  } else {
    int tb = bid - 6144;                       // 0..4095 (was grid 64x8x8)
    int t0 = (tb & 63) * 32, d0 = ((tb >> 6) & 7) * 32;
    int bz = tb >> 9;
    int b = bz >> 2, vh = bz & 3;
    int tx = threadIdx.x & 31, ty = threadIdx.x >> 5;
#pragma unroll
    for (int i = 0; i < 4; i++) {
      int t = t0 + ty + i * 8;
      tile[ty + i * 8][tx] = qkv[((size_t)(b * T_SEQ + t)) * NQKV + 3072 + vh * 256 + d0 + tx];
    }
    __syncthreads();
#pragma unroll
    for (int i = 0; i < 4; i++) {
      int d = d0 + ty + i * 8;
      vt[(((size_t)(b * 4 + vh)) * 256 + d) * T_SEQ + t0 + tx] = tile[tx][ty + i * 8];
    }
  }
}

// ---------------- causal flash attention v10: O^T accumulation (domain-matched softmax) ----------------
// = v9 (R8-proven, 108us) with PV operand order SWAPPED: mfma(vf, pf) instead of
// mfma(pf, vf). Since mfma(X,Y) = X·Y^T on this fragment layout (the property QK^T and
// gemm_nt already rely on), this computes O^T = V^T·P^T with IDENTICAL fragment loads.
// acc columns become query=l15 — the same lane-local domain as softmax — so the 4
// ds_bpermute alpha redistributions + 4 epilogue shuffles vanish (alpha/linv lane-local),
// and the epilogue becomes 16 float4/half4 stores (dims nb*16+quad*4..+3 contiguous).
__global__ __launch_bounds__(256) void attn(const _Float16* __restrict__ qkv,
                                            const _Float16* __restrict__ kp,
                                            const _Float16* __restrict__ vt,
                                            const float* __restrict__ scaler,
                                            float* __restrict__ y1out,
                                            _Float16* __restrict__ y2out) {
  __shared__ __align__(16) char Ks[2][64 * 256];   // 32 KB: K tile, dbuf (256B rows, swizzled)
  __shared__ __align__(16) char Vs[2][128 * 128];  // 32 KB: V^T halves (128B rows, swizzled)
  __shared__ _Float16 Pt[4 * 16 * 72];             // 9 KB: per-wave P (A-operand layout)
  // total LDS 74752 B -> 2 blocks/CU

  int tid = threadIdx.x, lane = tid & 63, w = tid >> 6;
  int l15 = lane & 15, quad = lane >> 4;
  int bx = blockIdx.x, hh = blockIdx.y, z = blockIdx.z;
  int b = z >> 1, br = z & 1;
  int qh = br * 8 + hh;
  int kh = br * 4 + (hh >> 1);
  int vh = hh >> 1;

  const char* kbase_b = (const char*)(kp + ((size_t)(b * 8 + kh)) * T_SEQ * 128);
  const char* vbase_b = (const char*)(vt + ((size_t)(b * 4 + vh)) * 256 * T_SEQ);
  _Float16* pw = &Pt[w * 16 * 72];
  float sc = scaler[qh] * 0.08838834764831844f; // 1/sqrt(128)

  // staging lane constants
  int krow_l = lane >> 4;          // row within 4-row K chunk
  int kpc    = (lane & 15) << 4;   // byte col within 256B K row
  int vrow_l = lane >> 3;          // row within 8-row V chunk
  int vpc    = (lane & 7) << 4;    // byte col within 128B V row

  // wave w stages K rows 16w..16w+15 (4 chunks x 1KB) and V dims 32w..32w+31 per half
  auto stageK = [&](int kt1) {
    int ksr = kt1 * 64;
    char* dstb = Ks[kt1 & 1];
#pragma unroll
    for (int c2 = 0; c2 < 4; c2++) {
      int cc = w * 4 + c2;
      int row = cc * 4 + krow_l;
      const char* src = kbase_b + (((size_t)(ksr + row)) << 8) + (kpc ^ ((row & 7) << 4));
      GLD16(src, dstb + (cc << 10));
    }
  };
  auto stageV = [&](int kt1) {
    int ksb = kt1 * 128; // key-start byte offset within a V row
#pragma unroll
    for (int h = 0; h < 2; h++)
#pragma unroll
      for (int c2 = 0; c2 < 4; c2++) {
        int cc = w * 4 + c2;
        int d = h * 128 + cc * 8 + vrow_l;
        const char* src = vbase_b + (size_t)d * (T_SEQ * 2) + ksb + (vpc ^ (vrow_l << 4));
        GLD16(src, Vs[h] + (cc << 10));
      }
  };

  for (int half = 0; half < 2; half++) {
    int qt = half ? (31 - bx) : bx;
    int t0 = qt * 64;
    int tg = t0 + w * 16 + l15;  // this lane's query row (swapped layout)

    // Q fragments (B-operand: n = lane&15, k = quad*8+j); q in-place, row stride NQKV
    const _Float16* qbase = qkv + ((size_t)(b * T_SEQ + tg)) * NQKV + qh * 128;
    half8 qf[4];
#pragma unroll
    for (int kc = 0; kc < 4; kc++)
      qf[kc] = *(const half8*)(qbase + kc * 32 + quad * 8);

    // prologue: async-stage tile 0 (prev half's last barrier guarantees buffers free)
    stageK(0);
    stageV(0);
    __builtin_amdgcn_sched_barrier(0);

    float mrow = NEG_BIG, lrow = 0.f;          // per-lane: query = lane&15 (log2 domain)
    float rowscale = sc * logf((float)(tg + 1)) * 1.44269504f;  // fold log2(e)
    f32x4 acc[16];                              // O^T: acc[nb][r] = O[q=l15][d=nb*16+quad*4+r]
#pragma unroll
    for (int nb = 0; nb < 16; nb++) acc[nb] = (f32x4){0.f, 0.f, 0.f, 0.f};

    for (int kt = 0; kt <= qt; kt++) {
      int ks = kt * 64;
      bool notlast = (kt < qt);

      // (A) K(kt) ready; V(kt) stays in flight
      asm volatile("s_waitcnt vmcnt(8)" ::: "memory");
      __builtin_amdgcn_s_barrier();
      __builtin_amdgcn_sched_barrier(0);
      if (notlast) stageK(kt + 1);

      // (B) S^T = K Q^T from LDS (swizzled ds_read_b128); row=key, col=query
      const char* kbuf = Ks[kt & 1];
      f32x4 sv[4];
#pragma unroll
      for (int j = 0; j < 4; j++) {
        int row = j * 16 + l15;
        int sw = (row & 7) << 4;
        const char* kr = kbuf + (row << 8);
        half8 kf0 = *(const half8*)(kr + (((quad << 4) + 0) ^ sw));
        half8 kf1 = *(const half8*)(kr + (((quad << 4) + 64) ^ sw));
        half8 kf2 = *(const half8*)(kr + (((quad << 4) + 128) ^ sw));
        half8 kf3 = *(const half8*)(kr + (((quad << 4) + 192) ^ sw));
        f32x4 a = (f32x4){0.f, 0.f, 0.f, 0.f};
        a = __builtin_amdgcn_mfma_f32_16x16x32_f16(kf0, qf[0], a, 0, 0, 0);
        a = __builtin_amdgcn_mfma_f32_16x16x32_f16(kf1, qf[1], a, 0, 0, 0);
        a = __builtin_amdgcn_mfma_f32_16x16x32_f16(kf2, qf[2], a, 0, 0, 0);
        a = __builtin_amdgcn_mfma_f32_16x16x32_f16(kf3, qf[3], a, 0, 0, 0);
        sv[j] = a;
      }

      // (C) softmax — lane-local over 16 scores of query l15 (log2 domain, straight-line)
      bool diag = (kt == qt);
      float s_r[16];
      float mx = NEG_BIG;
#pragma unroll
      for (int j = 0; j < 4; j++)
#pragma unroll
        for (int r = 0; r < 4; r++) {
          float s = sv[j][r] * rowscale;
          if (diag) {
            int kg = ks + j * 16 + quad * 4 + r;
            if (kg > tg) s = NEG_BIG;
          }
          s_r[j * 4 + r] = s;
          mx = fmaxf(mx, s);
        }
      mx = fmaxf(mx, __shfl_xor(mx, 16, 64));
      mx = fmaxf(mx, __shfl_xor(mx, 32, 64));
      float mnew = fmaxf(mrow, mx);
      float alpha = __builtin_amdgcn_exp2f(mrow - mnew);
      float p[16];
      float rs = 0.f;
#pragma unroll
      for (int i = 0; i < 16; i++) {
        p[i] = __builtin_amdgcn_exp2f(s_r[i] - mnew);
        rs += p[i];
      }
      rs += __shfl_xor(rs, 16, 64);
      rs += __shfl_xor(rs, 32, 64);
      lrow = lrow * alpha + rs;
      mrow = mnew;
      // O^T domain: alpha is lane-local (acc col = query = l15) — no redistribution needed
#pragma unroll
      for (int nb = 0; nb < 16; nb++)
#pragma unroll
        for (int r = 0; r < 4; r++) acc[nb][r] *= alpha;

      // (D) P -> LDS (packed b64) -> fragments (wave-private; no barrier)
#pragma unroll
      for (int j = 0; j < 4; j++) {
        half4 pk;
        pk[0] = (_Float16)p[j * 4 + 0];
        pk[1] = (_Float16)p[j * 4 + 1];
        pk[2] = (_Float16)p[j * 4 + 2];
        pk[3] = (_Float16)p[j * 4 + 3];
        *(half4*)&pw[l15 * 72 + j * 16 + quad * 4] = pk;
      }
      half8 pf0 = *(const half8*)&pw[l15 * 72 + quad * 8];
      half8 pf1 = *(const half8*)&pw[l15 * 72 + 32 + quad * 8];

      // (E) publish Vs: drain V(kt), keep K(kt+1) in flight
      if (notlast)
        asm volatile("s_waitcnt vmcnt(4)" ::: "memory");
      else
        asm volatile("s_waitcnt vmcnt(0)" ::: "memory");
      __builtin_amdgcn_s_barrier();
      __builtin_amdgcn_sched_barrier(0);

      // (F) O^T += V^T P^T from LDS (operand-swapped mfma; identical fragment reads)
#pragma unroll
      for (int h = 0; h < 2; h++) {
#pragma unroll
        for (int nbl = 0; nbl < 8; nbl++) {
          int row = nbl * 16 + l15;
          int sw = (row & 7) << 4;
          const char* vr = Vs[h] + (row << 7);
          half8 vf0 = *(const half8*)(vr + (((quad << 4) + 0) ^ sw));
          half8 vf1 = *(const half8*)(vr + (((quad << 4) + 64) ^ sw));
          int nb = h * 8 + nbl;
          acc[nb] = __builtin_amdgcn_mfma_f32_16x16x32_f16(vf0, pf0, acc[nb], 0, 0, 0);
          acc[nb] = __builtin_amdgcn_mfma_f32_16x16x32_f16(vf1, pf1, acc[nb], 0, 0, 0);
        }
      }

      // (G) Vs consumed by all waves -> prefetch V(kt+1)
      asm volatile("s_waitcnt lgkmcnt(0)" ::: "memory");
      __builtin_amdgcn_s_barrier();
      __builtin_amdgcn_sched_barrier(0);
      if (notlast) stageV(kt + 1);
    }

    // epilogue: divide by l (lane-local); O^T: query=l15, dims nb*16+quad*4..+3 contiguous
    float linv = 1.0f / lrow;
    size_t base = ((size_t)(b * T_SEQ + tg)) * 2048 + hh * 256 + quad * 4;
    if (br) {
#pragma unroll
      for (int nb = 0; nb < 16; nb++) {
        half4 hv;
        hv[0] = (_Float16)(acc[nb][0] * linv);
        hv[1] = (_Float16)(acc[nb][1] * linv);
        hv[2] = (_Float16)(acc[nb][2] * linv);
        hv[3] = (_Float16)(acc[nb][3] * linv);
        *(half4*)(y2out + base + nb * 16) = hv;
      }
    } else {
#pragma unroll
      for (int nb = 0; nb < 16; nb++) {
        float4 fv;
        fv.x = acc[nb][0] * linv;
        fv.y = acc[nb][1] * linv;
        fv.z = acc[nb][2] * linv;
        fv.w = acc[nb][3] * linv;
        *(float4*)(y1out + base + nb * 16) = fv;
      }
    }
  }
}

// ---------------- out = y1 - lam * y2 (f32, in place on d_out) ----------------
__global__ __launch_bounds__(256) void combine(float* __restrict__ out,
                                               const _Float16* __restrict__ y2,
                                               const float* __restrict__ lq1,
                                               const float* __restrict__ lk1,
                                               const float* __restrict__ lq2,
                                               const float* __restrict__ lk2) {
  int lane = threadIdx.x & 63;
  float a = lq1[lane] * lk1[lane];
  float bb = lq2[lane] * lk2[lane];
#pragma unroll
  for (int m = 1; m < 64; m <<= 1) {
    a += __shfl_xor(a, m, 64);
    bb += __shfl_xor(bb, m, 64);
  }
  float lam = expf(a) - expf(bb) + 0.2f;

  size_t o = ((size_t)blockIdx.x * 256 + threadIdx.x) * 8;
  half8 yv = *(const half8*)(y2 + o);
  float4 a0 = *(float4*)(out + o);
  float4 a1 = *(float4*)(out + o + 4);
  a0.x -= lam * (float)yv[0];
  a0.y -= lam * (float)yv[1];
  a0.z -= lam * (float)yv[2];
  a0.w -= lam * (float)yv[3];
  a1.x -= lam * (float)yv[4];
  a1.y -= lam * (float)yv[5];
  a1.z -= lam * (float)yv[6];
  a1.w -= lam * (float)yv[7];
  *(float4*)(out + o) = a0;
  *(float4*)(out + o + 4) = a1;
}

extern "C" void kernel_launch(void* const* d_in, const int* in_sizes, int n_in,
                              void* d_out, int out_size, void* d_ws, size_t ws_size,
                              hipStream_t stream) {
  const float* x   = (const float*)d_in[0];
  const float* Wq  = (const float*)d_in[1];
  const float* Wk  = (const float*)d_in[2];
  const float* Wv  = (const float*)d_in[3];
  const float* lq1 = (const float*)d_in[4];
  const float* lk1 = (const float*)d_in[5];
  const float* lq2 = (const float*)d_in[6];
  const float* lk2 = (const float*)d_in[7];
  const float* scaler = (const float*)d_in[8];
  float* out = (float*)d_out;

  char* W = (char*)d_ws;
  // Workspace high-water 64 MiB (proven safe):
  // Phase 1 (until gemm done): xh [0,16.78M), wh [16.78,33.55M), qkvh [33.55,67.11M)
  // Phase 2 (after gemm, xh/wh dead): kp [0,8.39M), vtb [8.39,16.78M), y2h [16.78,33.55M)
  // RoPE tables live in d_out[0, 1.05MB) (free until attn writes y1 there).
  _Float16* xh   = (_Float16*)(W + 0);
  _Float16* wh   = (_Float16*)(W + 16777216);
  _Float16* qkvh = (_Float16*)(W + 33554432);
  _Float16* kph  = (_Float16*)(W + 0);
  _Float16* vtb  = (_Float16*)(W + 8388608);
  _Float16* y2h  = (_Float16*)(W + 16777216);
  float* cosT    = out;            // 2048*64 f32 = 0.52 MB
  float* sinT    = out + 131072;   // 0.52 MB (ends at 1.05 MB)

  prep<<<10240, 256, 0, stream>>>(x, Wq, Wk, Wv, xh, wh, cosT, sinT);
  gemm_nt<<<dim3(NQKV / 128, MROWS / 128), 256, 0, stream>>>(xh, wh, qkvh);
  mid<<<10240, 256, 0, stream>>>(qkvh, cosT, sinT, kph, vtb);
  attn<<<dim3(16, 8, BSZ * 2), 256, 0, stream>>>(qkvh, kph, vtb, scaler, out, y2h);
  combine<<<4096, 256, 0, stream>>>(out, y2h, lq1, lk1, lq2, lk2);
}